// Round 4
// baseline (195.013 us; speedup 1.0000x reference)
//
#include <hip/hip_runtime.h>
#include <hip/hip_bf16.h>

// MultiHeadAttention: B=2, S=2048, H=16, D=64, E=1024. f32 I/O, bf16 internal.
// R14 vs R13 (193.2us; attn top at 43.2us: MfmaUtil 15.4, VALUBusy 44 =>
// VALU/latency-bound on the softmax->PV operand exchange):
//  * attn: replace the 16 __shfl_xor(ds_bpermute) + 16 cndmask per tile with
//    8 v_permlane32_swap_b32 (T12). swap(a,b) yields a = hi?b[l-32]:a and
//    b = hi?b:a[l+32] == pf.u[0]/pf.u[2] directly - pure VALU, no LDS pipe
//    on the critical path.
//  * attn: even-qt blocks' last j-tile jh==1 half is fully causal-masked;
//    skip its S^T/softmax/PV (wave-uniform branch; barriers/staging kept).
//  * GEMMs (gload_lds BK=32 dbuf + XOR swizzle) / prep: unchanged from R13.

typedef __hip_bfloat16 bf16;
typedef __attribute__((ext_vector_type(8))) short bfrag;    // 8 bf16 = 4 VGPRs
typedef __attribute__((ext_vector_type(4))) float f32x4;
typedef __attribute__((ext_vector_type(16))) float f32x16;  // 32x32 C/D
typedef __attribute__((ext_vector_type(4))) short short4v;

#define MFMA16(a, b, c) __builtin_amdgcn_mfma_f32_16x16x32_bf16(a, b, c, 0, 0, 0)
#define MFMA32(a, b, c) __builtin_amdgcn_mfma_f32_32x32x16_bf16(a, b, c, 0, 0, 0)

__device__ __forceinline__ unsigned pkbf(float a, float b) {
  union { bf16 h[2]; unsigned u; } w;
  w.h[0] = __float2bfloat16(a);
  w.h[1] = __float2bfloat16(b);
  return w.u;
}

// async global->LDS, 16B per lane; LDS dest = wave-uniform base + lane*16.
__device__ __forceinline__ void gload16(const bf16* g, bf16* l) {
  __builtin_amdgcn_global_load_lds(
      (const __attribute__((address_space(1))) void*)(g),
      (__attribute__((address_space(3))) void*)(l), 16, 0, 0);
}

// ---------------- fused cast + weight transposes --------------------------
// blocks 0..2047: x f32->bf16. 2048..2815: Wq/Wk/Wv -> WqkvT. 2816..3071: Wo.
__global__ __launch_bounds__(256) void prep_all(const float* __restrict__ x,
                                                const float* __restrict__ Wq,
                                                const float* __restrict__ Wk,
                                                const float* __restrict__ Wv,
                                                const float* __restrict__ Wo,
                                                bf16* __restrict__ xb,
                                                bf16* __restrict__ WqkvT,
                                                bf16* __restrict__ WoT) {
  __shared__ bf16 tile[64][80];
  int id = blockIdx.x;
  int t = threadIdx.x;
  if (id < 2048) {
    int i = id * 2048 + t * 8;
    float4 a = *(const float4*)(x + i);
    float4 b = *(const float4*)(x + i + 4);
    union { bf16 h[8]; bfrag v; } tmp;
    tmp.h[0] = __float2bfloat16(a.x); tmp.h[1] = __float2bfloat16(a.y);
    tmp.h[2] = __float2bfloat16(a.z); tmp.h[3] = __float2bfloat16(a.w);
    tmp.h[4] = __float2bfloat16(b.x); tmp.h[5] = __float2bfloat16(b.y);
    tmp.h[6] = __float2bfloat16(b.z); tmp.h[7] = __float2bfloat16(b.w);
    *(bfrag*)(xb + i) = tmp.v;
    return;
  }
  int wid = id - 2048;
  const float* src;
  bf16* dst;
  int srcld, dstld, r0, c0;
  if (wid < 768) {
    int w = wid >> 8, h = (wid >> 4) & 15;
    r0 = (wid & 15) * 64; c0 = 0;
    src = ((w == 0) ? Wq : (w == 1) ? Wk : Wv) + (long)h * 1024 * 64;
    dst = WqkvT + ((long)w * 1024 + h * 64) * 1024;
    srcld = 64; dstld = 1024;
  } else {
    int j = wid - 768;
    c0 = (j & 15) * 64; r0 = (j >> 4) * 64;
    src = Wo; dst = WoT;
    srcld = 1024; dstld = 1024;
  }
  int lr = t >> 3, lc = (t & 7) << 3;
#pragma unroll
  for (int p = 0; p < 2; ++p) {
    int r = lr + p * 32;
    const float* s = src + (long)(r0 + r) * srcld + c0 + lc;
    union { bf16 h8[8]; bfrag v; } tmp;
#pragma unroll
    for (int j = 0; j < 8; ++j) tmp.h8[j] = __float2bfloat16(s[j]);
    *(bfrag*)(&tile[r][lc]) = tmp.v;
  }
  __syncthreads();
#pragma unroll
  for (int p = 0; p < 2; ++p) {
    int c = lr + p * 32;
    union { bf16 h8[8]; bfrag v; } tmp;
#pragma unroll
    for (int j = 0; j < 8; ++j) tmp.h8[j] = tile[lc + j][c];
    *(bfrag*)(dst + (long)(c0 + c) * dstld + r0 + lc) = tmp.v;
  }
}

// ---------------- fused QKV GEMM: 128x128, BK=32, gload_lds dbuf ----------
// Q/K head-major [b][h][s][d]; V [b][h][d][s]. Direct-store epilogue (R8).
// LDS tile [128][32] linear, swizzled: slot s of row r holds chunk s^(r&3).
__global__ __launch_bounds__(256) void gemm_qkv128(const bf16* __restrict__ xb,
                                                   const bf16* __restrict__ WT,
                                                   const float* __restrict__ bq,
                                                   const float* __restrict__ bk,
                                                   const float* __restrict__ bv,
                                                   bf16* __restrict__ Q,
                                                   bf16* __restrict__ K_,
                                                   bf16* __restrict__ Vt) {
  const int K = 1024;
  __shared__ bf16 As[2][128 * 32];
  __shared__ bf16 Bs[2][128 * 32];
  int id = blockIdx.x;
  int xcd = id & 7, sw = id >> 3;
  int m0 = ((xcd << 2) | (sw & 3)) * 128;
  int n0 = (sw >> 2) * 128;
  int t = threadIdx.x, wave = t >> 6, lane = t & 63, quad = lane >> 4, col = lane & 15;
  int wr = (wave >> 1) * 64, wc = (wave & 1) * 64;
  f32x4 acc[4][4] = {};

  // staging: wave w covers rows [32w,32w+32) of A and B; 2 gload16 each.
  // lane: row = r0 + (l>>2), pre-swizzled source chunk = (l&3)^((l>>2)&3).
  int schunk = (lane & 3) ^ ((lane >> 2) & 3);
  const bf16* Asrc = xb + (long)(m0 + wave * 32 + (lane >> 2)) * K + schunk * 8;
  const bf16* Bsrc = WT + (long)(n0 + wave * 32 + (lane >> 2)) * K + schunk * 8;
  int l0 = (wave * 32) * 32;       // wave-uniform LDS element base
  int rdoff = ((quad ^ (col & 3)) << 3);

#define QKV_STAGE(bi, koff)                                    \
  {                                                            \
    gload16(Asrc + (koff), &As[bi][l0]);                       \
    gload16(Asrc + (koff) + 16 * K, &As[bi][l0 + 16 * 32]);    \
    gload16(Bsrc + (koff), &Bs[bi][l0]);                       \
    gload16(Bsrc + (koff) + 16 * K, &Bs[bi][l0 + 16 * 32]);    \
  }

  QKV_STAGE(0, 0);
  __syncthreads();
  for (int k0 = 0; k0 < K; k0 += 32) {
    int cur = (k0 >> 5) & 1;
    if (k0 + 32 < K) QKV_STAGE(cur ^ 1, k0 + 32);
    bfrag ra[4], rb[4];
#pragma unroll
    for (int i = 0; i < 4; ++i)
      ra[i] = *(const bfrag*)(&As[cur][(wr + 16 * i + col) * 32 + rdoff]);
#pragma unroll
    for (int c = 0; c < 4; ++c)
      rb[c] = *(const bfrag*)(&Bs[cur][(wc + 16 * c + col) * 32 + rdoff]);
#pragma unroll
    for (int c = 0; c < 4; ++c)
#pragma unroll
      for (int i = 0; i < 4; ++i) acc[c][i] = MFMA16(ra[i], rb[c], acc[c][i]);
    __syncthreads();
  }
#undef QKV_STAGE

  int sel = n0 >> 10;   // 0=Q, 1=K, 2=V
  const float* bias = (sel == 0) ? bq : (sel == 1) ? bk : bv;
#pragma unroll
  for (int c = 0; c < 4; ++c) {
    int nn = (n0 + wc + 16 * c + col) & 1023;
    float bvv = bias[nn];
    int h = nn >> 6, d = nn & 63;
#pragma unroll
    for (int i = 0; i < 4; ++i) {
      int mb = m0 + wr + 16 * i + quad * 4;
      int b = mb >> 11, s0 = mb & 2047;
      if (sel < 2) {
        bf16* dst = (sel == 0) ? Q : K_;
        long base = ((long)((b << 4) + h) * 2048 + s0) * 64 + d;
#pragma unroll
        for (int r = 0; r < 4; ++r)
          dst[base + (long)r * 64] = __float2bfloat16(acc[c][i][r] + bvv);
      } else {
        union { bf16 h4[4]; short4v v; } pk;
#pragma unroll
        for (int r = 0; r < 4; ++r) pk.h4[r] = __float2bfloat16(acc[c][i][r] + bvv);
        *(short4v*)(Vt + (long)(((b << 4) + h) * 64 + d) * 2048 + s0) = pk.v;
      }
    }
  }
}

// ---------------- out-projection: 128x64, BK=32, gload_lds dbuf -----------
__global__ __launch_bounds__(256) void gemm_out(const bf16* __restrict__ O,
                                                const bf16* __restrict__ Bt,
                                                float* __restrict__ Cf) {
  const int K = 1024;
  __shared__ bf16 As[2][128 * 32];
  __shared__ bf16 Bs[2][64 * 32];
  int id = blockIdx.x;
  int xcd = id & 7, sw = id >> 3;
  int m0 = ((xcd << 2) | (sw & 3)) * 128;
  int n0 = (sw >> 2) * 64;
  int t = threadIdx.x;
  int wave = t >> 6, lane = t & 63, quad = lane >> 4, col = lane & 15;
  int wr = (wave >> 1) * 64, wc = (wave & 1) * 32;
  f32x4 acc[2][4] = {};

  // staging: wave w covers A rows [32w,+32) (2 instr), B rows [16w,+16) (1).
  int schunk = (lane & 3) ^ ((lane >> 2) & 3);
  int arow = m0 + wave * 32 + (lane >> 2);
  int ob = arow >> 11, os = arow & 2047;
  // A = O[b][h][s][d]: row m=(b,s), col k=(h,d); koff(k0)=(k0>>6)*131072+(k0&32)
  const bf16* Asrc = O + (long)ob * 2097152 + (long)os * 64 + schunk * 8;
  const bf16* Bsrc = Bt + (long)(n0 + wave * 16 + (lane >> 2)) * K + schunk * 8;
  int la0 = (wave * 32) * 32;
  int lb0 = (wave * 16) * 32;
  int rdoff = ((quad ^ (col & 3)) << 3);

#define OUT_STAGE(bi, k0n)                                            \
  {                                                                   \
    long ka = ((long)((k0n) >> 6)) * 131072 + ((k0n) & 32);           \
    gload16(Asrc + ka, &As[bi][la0]);                                 \
    gload16(Asrc + ka + 16 * 64, &As[bi][la0 + 16 * 32]);             \
    gload16(Bsrc + (k0n), &Bs[bi][lb0]);                              \
  }

  OUT_STAGE(0, 0);
  __syncthreads();
  for (int k0 = 0; k0 < K; k0 += 32) {
    int cur = (k0 >> 5) & 1;
    if (k0 + 32 < K) OUT_STAGE(cur ^ 1, k0 + 32);
    bfrag ra[4], rb[2];
#pragma unroll
    for (int i = 0; i < 4; ++i)
      ra[i] = *(const bfrag*)(&As[cur][(wr + 16 * i + col) * 32 + rdoff]);
#pragma unroll
    for (int c = 0; c < 2; ++c)
      rb[c] = *(const bfrag*)(&Bs[cur][(wc + 16 * c + col) * 32 + rdoff]);
#pragma unroll
    for (int c = 0; c < 2; ++c)
#pragma unroll
      for (int i = 0; i < 4; ++i) acc[c][i] = MFMA16(ra[i], rb[c], acc[c][i]);
    __syncthreads();
  }
#undef OUT_STAGE

#pragma unroll
  for (int c = 0; c < 2; ++c) {
    int n = n0 + wc + 16 * c + col;
#pragma unroll
    for (int i = 0; i < 4; ++i)
#pragma unroll
      for (int r = 0; r < 4; ++r) {
        int m = m0 + wr + 16 * i + quad * 4 + r;
        Cf[(long)m * 1024 + n] = acc[c][i][r];
      }
  }
}

// ---------------- flash attention: S^T dataflow, 2-barrier pipeline -------
// Q/K head-major [b][h][s][d]; Vt [b][h][d][s]; O head-major.
// S^T = MFMA32(A=K_rows, B=Q_rows): C cols = q (lanes), rows = j (regs).
// P^T feeds PV's B operand in-register via v_permlane32_swap_b32:
//   swap(a,b): a' = hi ? b[l-32] : a ; b' = hi ? b : a[l+32]  (= pf.u pair).
// O^T = MFMA32(A=V^T from Vs[d][j], B=P^T): cols = q, rows = d.
// kreg AND vreg prefetched one full j-tile ahead; both staged at loop top =>
// 2 barriers/iter; S^T->softmax->PV barrier-free. Even-qt blocks skip the
// fully-masked jh==1 half of their last j-tile.
__global__ __launch_bounds__(256) void attn_kernel(const bf16* __restrict__ Q,
                                                   const bf16* __restrict__ K_,
                                                   const bf16* __restrict__ Vt,
                                                   bf16* __restrict__ O) {
  int id = blockIdx.x;             // 1024 blocks
  int xcd = id & 7, jj = id >> 3;
  int qt = 31 - (jj >> 2);         // LPT
  int bh = ((jj & 3) << 3) | xcd;  // 4 bh per XCD

  __shared__ bf16 Ks[128][72];     // [j][d]; f32 Osc[64][68] overlay in epilogue
  __shared__ bf16 Vs[64][136];     // [d][j]; Lsc + Of overlay in epilogue

  int t = threadIdx.x, wave = t >> 6, lane = t & 63;
  int qh = wave >> 1, jh = wave & 1, hi = lane >> 5, l5 = lane & 31;

  const float SC2 = 0.18033688f;   // (1/8)*log2(e); p = exp2(s*SC2 - 16)

  int krow = t >> 3, kg = (t & 7) * 8;
  int vrow = t >> 4, vg = (t & 15) * 8;
  const bf16* Kbase = K_ + ((long)bh * 2048 + krow) * 64 + kg;
  const bf16* Vbase = Vt + ((long)bh * 64 + vrow) * 2048 + vg;

  int q0 = qt * 64;
  int nj = (qt >> 1) + 1;
  int qi = q0 + 32 * qh + l5;      // this lane's global q index

  bfrag qa[4];
  const bf16* qp = Q + ((long)bh * 2048 + q0 + 32 * qh + l5) * 64 + hi * 8;
#pragma unroll
  for (int kd = 0; kd < 4; ++kd) qa[kd] = *(const bfrag*)(qp + kd * 16);

  f32x16 o0, o1;                   // O^T partials: rows d / d+32, col q
  float lsum = 0.f;                // per-lane: sum over this wave's j-half
#pragma unroll
  for (int r = 0; r < 16; ++r) { o0[r] = 0.f; o1[r] = 0.f; }

  // prefetch j-tile 0 (both K and V)
  bfrag kreg[4], vreg[4];
#pragma unroll
  for (int i = 0; i < 4; ++i) {
    kreg[i] = *(const bfrag*)(Kbase + (long)(32 * i) * 64);
    vreg[i] = *(const bfrag*)(Vbase + (long)(16 * i) * 2048);
  }

  for (int jt = 0; jt < nj; ++jt) {
    int j0 = jt * 128;
    __syncthreads();               // prev iter's Ks/Vs reads complete
#pragma unroll
    for (int i = 0; i < 4; ++i) {
      *(bfrag*)(&Ks[krow + 32 * i][kg]) = kreg[i];
      *(bfrag*)(&Vs[vrow + 16 * i][vg]) = vreg[i];
    }
    int jn = (jt + 1 < nj) ? (jt + 1) * 128 : jt * 128;
#pragma unroll
    for (int i = 0; i < 4; ++i) {
      kreg[i] = *(const bfrag*)(Kbase + (long)(jn + 32 * i) * 64);
      vreg[i] = *(const bfrag*)(Vbase + (long)(16 * i) * 2048 + jn);
    }
    __syncthreads();               // Ks/Vs ready for all waves

    bool lastT = (jt == nj - 1);
    // even qt: last tile's jh==1 half (j in [q0+64,q0+128)) is fully masked.
    if (lastT && jh == 1 && ((qt & 1) == 0)) continue;

    // S^T: per wave 64j (own half) x 32q. A = K rows, B = Q rows.
    f32x16 s0, s1;
#pragma unroll
    for (int r = 0; r < 16; ++r) { s0[r] = 0.f; s1[r] = 0.f; }
    __builtin_amdgcn_s_setprio(1);
#pragma unroll
    for (int kd = 0; kd < 4; ++kd) {
      bfrag ka0 = *(const bfrag*)(&Ks[jh * 64 + l5][kd * 16 + hi * 8]);
      bfrag ka1 = *(const bfrag*)(&Ks[jh * 64 + 32 + l5][kd * 16 + hi * 8]);
      s0 = MFMA32(ka0, qa[kd], s0);
      s1 = MFMA32(ka1, qa[kd], s1);
    }
    __builtin_amdgcn_s_setprio(0);

    // softmax in-register; pack P^T bf16 groups (g[jb][0..3] = r0-3,4-7,8-11,12-15)
    unsigned g[2][4][2];
#pragma unroll
    for (int jb = 0; jb < 2; ++jb) {
      float pv[16];
      float ls = 0.f;
#pragma unroll
      for (int r = 0; r < 16; ++r) {
        int jl = (r & 3) + 8 * (r >> 2) + 4 * hi;        // j within 32-block
        int j = j0 + jh * 64 + jb * 32 + jl;
        float sv = jb ? s1[r] : s0[r];
        float p = __builtin_amdgcn_exp2f(fmaf(sv, SC2, -16.0f));
        if (lastT) p = (j <= qi) ? p : 0.f;
        ls += p;
        pv[r] = p;
      }
      lsum += ls;
#pragma unroll
      for (int gg = 0; gg < 4; ++gg) {
        g[jb][gg][0] = pkbf(pv[4 * gg], pv[4 * gg + 1]);
        g[jb][gg][1] = pkbf(pv[4 * gg + 2], pv[4 * gg + 3]);
      }
    }

    // PV: O^T += V^T * P^T over own j-half
    __builtin_amdgcn_s_setprio(1);
#pragma unroll
    for (int jb = 0; jb < 2; ++jb) {
#pragma unroll
      for (int c = 0; c < 2; ++c) {
        // B-frag jj0..7 for k-chunk c: groups 2c (r-lo) and 2c+1 (r-hi).
        // One permlane32_swap per register pair builds both pf halves.
        unsigned a0 = g[jb][2 * c][0], a1 = g[jb][2 * c][1];
        unsigned b0 = g[jb][2 * c + 1][0], b1 = g[jb][2 * c + 1][1];
        asm("v_permlane32_swap_b32 %0, %1" : "+v"(a0), "+v"(b0));
        asm("v_permlane32_swap_b32 %0, %1" : "+v"(a1), "+v"(b1));
        union { unsigned u[4]; bfrag f; } pf;
        pf.u[0] = a0;
        pf.u[1] = a1;
        pf.u[2] = b0;
        pf.u[3] = b1;
        int kk = jh * 64 + jb * 32 + c * 16 + hi * 8;
        bfrag av0 = *(const bfrag*)(&Vs[l5][kk]);
        bfrag av1 = *(const bfrag*)(&Vs[32 + l5][kk]);
        o0 = MFMA32(av0, pf.f, o0);
        o1 = MFMA32(av1, pf.f, o1);
      }
    }
    __builtin_amdgcn_s_setprio(0);
  }

  // combine hi-halves of lsum (same q, different j-sets)
  lsum += __shfl_xor(lsum, 32, 64);

  __syncthreads();   // all Ks/Vs reads done; overlay scratch
  float* Osc = (float*)&Ks[0][0];                    // [64 q][68 d]
  float* Lsc = (float*)&Vs[0][0];                    // [64 q]
  bf16* Of = (bf16*)((char*)&Vs[0][0] + 512);        // [64 q][72 d]
  int q = 32 * qh + l5;
  if (jh == 1) {
#pragma unroll
    for (int r = 0; r < 16; ++r) {
      int d = (r & 3) + 8 * (r >> 2) + 4 * hi;
      Osc[q * 68 + d] = o0[r];
      Osc[q * 68 + 32 + d] = o1[r];
    }
    if (hi == 0) Lsc[q] = lsum;
  }
  __syncthreads();
  if (jh == 0) {
    float inv = 1.f / (lsum + Lsc[q]);
#pragma unroll
    for (int r = 0; r < 16; ++r) {
      int d = (r & 3) + 8 * (r >> 2) + 4 * hi;
      Of[q * 72 + d] = __float2bfloat16((o0[r] + Osc[q * 68 + d]) * inv);
      Of[q * 72 + 32 + d] = __float2bfloat16((o1[r] + Osc[q * 68 + 32 + d]) * inv);
    }
  }
  __syncthreads();
  int row = t >> 2, off = (t & 3) * 16;
  bf16* po = O + ((long)bh * 2048 + q0 + row) * 64 + off;
  *(bfrag*)(po) = *(const bfrag*)(&Of[row * 72 + off]);
  *(bfrag*)(po + 8) = *(const bfrag*)(&Of[row * 72 + off + 8]);
}

extern "C" void kernel_launch(void* const* d_in, const int* in_sizes, int n_in,
                              void* d_out, int out_size, void* d_ws, size_t ws_size,
                              hipStream_t stream) {
  const float* x  = (const float*)d_in[0];
  const float* Wq = (const float*)d_in[1];
  const float* bq = (const float*)d_in[2];
  const float* Wk = (const float*)d_in[3];
  const float* bk = (const float*)d_in[4];
  const float* Wv = (const float*)d_in[5];
  const float* bv = (const float*)d_in[6];
  const float* Wo = (const float*)d_in[7];
  float* out = (float*)d_out;

  bf16* ws = (bf16*)d_ws;
  const long MB1 = 1 << 20;
  bf16* WqkvT = ws + 0 * MB1;    // [3072][1024]
  bf16* WoT   = ws + 3 * MB1;
  bf16* Q     = ws + 4 * MB1;    // [b][h][s][d]
  bf16* K_    = ws + 8 * MB1;    // [b][h][s][d]
  bf16* Vt    = ws + 12 * MB1;   // [b][h][d][s]
  bf16* O     = ws + 16 * MB1;   // [b][h][s][d]
  bf16* xb    = ws + 20 * MB1;

  prep_all<<<3072, 256, 0, stream>>>(x, Wq, Wk, Wv, Wo, xb, WqkvT, WoT);
  gemm_qkv128<<<768, 256, 0, stream>>>(xb, WqkvT, bq, bk, bv, Q, K_, Vt);
  attn_kernel<<<1024, 256, 0, stream>>>(Q, K_, Vt, O);
  gemm_out<<<512, 256, 0, stream>>>(O, WoT, out);
}

// Round 5
// 194.767 us; speedup vs baseline: 1.0013x; 1.0013x over previous
//
#include <hip/hip_runtime.h>
#include <hip/hip_bf16.h>

// MultiHeadAttention: B=2, S=2048, H=16, D=64, E=1024. f32 I/O, bf16 internal.
// R15 vs R14 (195.0us; attn 44.6us, VALUBusy 43% = ~650 VALU instr/wave-iter
// vs ~180 of core softmax math => VALU bloat, not shuffles):
//  * Q pre-scaled by (1/8)*log2(e) in gemm_qkv epilogue; softmax drops the
//    fmaf(s,SC2,-16) -> bare v_exp_f32 (the -16 bias cancels in lsum division).
//  * P bf16 pack via __float22bfloat162_rn (v_cvt_pk_bf16_f32) instead of
//    scalar __float2bfloat16 pairs.
//  * Prefetch loads use wave-uniform base (jn advanced uniformly) + constant
//    lane offset => SGPR-base global_load, SALU-only per-iter address update.
//  * Everything else frozen (R14 permlane PV exchange, 2-barrier pipeline,
//    gload_lds GEMMs, masked-half skip).

typedef __hip_bfloat16 bf16;
typedef __attribute__((ext_vector_type(8))) short bfrag;    // 8 bf16 = 4 VGPRs
typedef __attribute__((ext_vector_type(4))) float f32x4;
typedef __attribute__((ext_vector_type(16))) float f32x16;  // 32x32 C/D
typedef __attribute__((ext_vector_type(4))) short short4v;

#define MFMA16(a, b, c) __builtin_amdgcn_mfma_f32_16x16x32_bf16(a, b, c, 0, 0, 0)
#define MFMA32(a, b, c) __builtin_amdgcn_mfma_f32_32x32x16_bf16(a, b, c, 0, 0, 0)

__device__ __forceinline__ unsigned pk2(float a, float b) {
  union { __hip_bfloat162 h; unsigned u; } w;
  w.h = __float22bfloat162_rn(make_float2(a, b));
  return w.u;
}

// async global->LDS, 16B per lane; LDS dest = wave-uniform base + lane*16.
__device__ __forceinline__ void gload16(const bf16* g, bf16* l) {
  __builtin_amdgcn_global_load_lds(
      (const __attribute__((address_space(1))) void*)(g),
      (__attribute__((address_space(3))) void*)(l), 16, 0, 0);
}

// ---------------- fused cast + weight transposes --------------------------
// blocks 0..2047: x f32->bf16. 2048..2815: Wq/Wk/Wv -> WqkvT. 2816..3071: Wo.
__global__ __launch_bounds__(256) void prep_all(const float* __restrict__ x,
                                                const float* __restrict__ Wq,
                                                const float* __restrict__ Wk,
                                                const float* __restrict__ Wv,
                                                const float* __restrict__ Wo,
                                                bf16* __restrict__ xb,
                                                bf16* __restrict__ WqkvT,
                                                bf16* __restrict__ WoT) {
  __shared__ bf16 tile[64][80];
  int id = blockIdx.x;
  int t = threadIdx.x;
  if (id < 2048) {
    int i = id * 2048 + t * 8;
    float4 a = *(const float4*)(x + i);
    float4 b = *(const float4*)(x + i + 4);
    union { bf16 h[8]; bfrag v; } tmp;
    tmp.h[0] = __float2bfloat16(a.x); tmp.h[1] = __float2bfloat16(a.y);
    tmp.h[2] = __float2bfloat16(a.z); tmp.h[3] = __float2bfloat16(a.w);
    tmp.h[4] = __float2bfloat16(b.x); tmp.h[5] = __float2bfloat16(b.y);
    tmp.h[6] = __float2bfloat16(b.z); tmp.h[7] = __float2bfloat16(b.w);
    *(bfrag*)(xb + i) = tmp.v;
    return;
  }
  int wid = id - 2048;
  const float* src;
  bf16* dst;
  int srcld, dstld, r0, c0;
  if (wid < 768) {
    int w = wid >> 8, h = (wid >> 4) & 15;
    r0 = (wid & 15) * 64; c0 = 0;
    src = ((w == 0) ? Wq : (w == 1) ? Wk : Wv) + (long)h * 1024 * 64;
    dst = WqkvT + ((long)w * 1024 + h * 64) * 1024;
    srcld = 64; dstld = 1024;
  } else {
    int j = wid - 768;
    c0 = (j & 15) * 64; r0 = (j >> 4) * 64;
    src = Wo; dst = WoT;
    srcld = 1024; dstld = 1024;
  }
  int lr = t >> 3, lc = (t & 7) << 3;
#pragma unroll
  for (int p = 0; p < 2; ++p) {
    int r = lr + p * 32;
    const float* s = src + (long)(r0 + r) * srcld + c0 + lc;
    union { bf16 h8[8]; bfrag v; } tmp;
#pragma unroll
    for (int j = 0; j < 8; ++j) tmp.h8[j] = __float2bfloat16(s[j]);
    *(bfrag*)(&tile[r][lc]) = tmp.v;
  }
  __syncthreads();
#pragma unroll
  for (int p = 0; p < 2; ++p) {
    int c = lr + p * 32;
    union { bf16 h8[8]; bfrag v; } tmp;
#pragma unroll
    for (int j = 0; j < 8; ++j) tmp.h8[j] = tile[lc + j][c];
    *(bfrag*)(dst + (long)(c0 + c) * dstld + r0 + lc) = tmp.v;
  }
}

// ---------------- fused QKV GEMM: 128x128, BK=32, gload_lds dbuf ----------
// Q/K head-major [b][h][s][d]; V [b][h][d][s]. Direct-store epilogue (R8).
// LDS tile [128][32] linear, swizzled: slot s of row r holds chunk s^(r&3).
// Q output pre-scaled by (1/8)*log2(e) for the attn exp2.
__global__ __launch_bounds__(256) void gemm_qkv128(const bf16* __restrict__ xb,
                                                   const bf16* __restrict__ WT,
                                                   const float* __restrict__ bq,
                                                   const float* __restrict__ bk,
                                                   const float* __restrict__ bv,
                                                   bf16* __restrict__ Q,
                                                   bf16* __restrict__ K_,
                                                   bf16* __restrict__ Vt) {
  const int K = 1024;
  __shared__ bf16 As[2][128 * 32];
  __shared__ bf16 Bs[2][128 * 32];
  int id = blockIdx.x;
  int xcd = id & 7, sw = id >> 3;
  int m0 = ((xcd << 2) | (sw & 3)) * 128;
  int n0 = (sw >> 2) * 128;
  int t = threadIdx.x, wave = t >> 6, lane = t & 63, quad = lane >> 4, col = lane & 15;
  int wr = (wave >> 1) * 64, wc = (wave & 1) * 64;
  f32x4 acc[4][4] = {};

  // staging: wave w covers rows [32w,32w+32) of A and B; 2 gload16 each.
  // lane: row = r0 + (l>>2), pre-swizzled source chunk = (l&3)^((l>>2)&3).
  int schunk = (lane & 3) ^ ((lane >> 2) & 3);
  const bf16* Asrc = xb + (long)(m0 + wave * 32 + (lane >> 2)) * K + schunk * 8;
  const bf16* Bsrc = WT + (long)(n0 + wave * 32 + (lane >> 2)) * K + schunk * 8;
  int l0 = (wave * 32) * 32;       // wave-uniform LDS element base
  int rdoff = ((quad ^ (col & 3)) << 3);

#define QKV_STAGE(bi, koff)                                    \
  {                                                            \
    gload16(Asrc + (koff), &As[bi][l0]);                       \
    gload16(Asrc + (koff) + 16 * K, &As[bi][l0 + 16 * 32]);    \
    gload16(Bsrc + (koff), &Bs[bi][l0]);                       \
    gload16(Bsrc + (koff) + 16 * K, &Bs[bi][l0 + 16 * 32]);    \
  }

  QKV_STAGE(0, 0);
  __syncthreads();
  for (int k0 = 0; k0 < K; k0 += 32) {
    int cur = (k0 >> 5) & 1;
    if (k0 + 32 < K) QKV_STAGE(cur ^ 1, k0 + 32);
    bfrag ra[4], rb[4];
#pragma unroll
    for (int i = 0; i < 4; ++i)
      ra[i] = *(const bfrag*)(&As[cur][(wr + 16 * i + col) * 32 + rdoff]);
#pragma unroll
    for (int c = 0; c < 4; ++c)
      rb[c] = *(const bfrag*)(&Bs[cur][(wc + 16 * c + col) * 32 + rdoff]);
#pragma unroll
    for (int c = 0; c < 4; ++c)
#pragma unroll
      for (int i = 0; i < 4; ++i) acc[c][i] = MFMA16(ra[i], rb[c], acc[c][i]);
    __syncthreads();
  }
#undef QKV_STAGE

  int sel = n0 >> 10;   // 0=Q, 1=K, 2=V
  const float* bias = (sel == 0) ? bq : (sel == 1) ? bk : bv;
  float qs = (sel == 0) ? 0.18033688f : 1.0f;   // (1/8)*log2(e) folded into Q
#pragma unroll
  for (int c = 0; c < 4; ++c) {
    int nn = (n0 + wc + 16 * c + col) & 1023;
    float bvv = bias[nn];
    int h = nn >> 6, d = nn & 63;
#pragma unroll
    for (int i = 0; i < 4; ++i) {
      int mb = m0 + wr + 16 * i + quad * 4;
      int b = mb >> 11, s0 = mb & 2047;
      if (sel < 2) {
        bf16* dst = (sel == 0) ? Q : K_;
        long base = ((long)((b << 4) + h) * 2048 + s0) * 64 + d;
#pragma unroll
        for (int r = 0; r < 4; ++r)
          dst[base + (long)r * 64] = __float2bfloat16((acc[c][i][r] + bvv) * qs);
      } else {
        union { bf16 h4[4]; short4v v; } pk;
#pragma unroll
        for (int r = 0; r < 4; ++r) pk.h4[r] = __float2bfloat16(acc[c][i][r] + bvv);
        *(short4v*)(Vt + (long)(((b << 4) + h) * 64 + d) * 2048 + s0) = pk.v;
      }
    }
  }
}

// ---------------- out-projection: 128x64, BK=32, gload_lds dbuf -----------
__global__ __launch_bounds__(256) void gemm_out(const bf16* __restrict__ O,
                                                const bf16* __restrict__ Bt,
                                                float* __restrict__ Cf) {
  const int K = 1024;
  __shared__ bf16 As[2][128 * 32];
  __shared__ bf16 Bs[2][64 * 32];
  int id = blockIdx.x;
  int xcd = id & 7, sw = id >> 3;
  int m0 = ((xcd << 2) | (sw & 3)) * 128;
  int n0 = (sw >> 2) * 64;
  int t = threadIdx.x;
  int wave = t >> 6, lane = t & 63, quad = lane >> 4, col = lane & 15;
  int wr = (wave >> 1) * 64, wc = (wave & 1) * 32;
  f32x4 acc[2][4] = {};

  // staging: wave w covers A rows [32w,+32) (2 instr), B rows [16w,+16) (1).
  int schunk = (lane & 3) ^ ((lane >> 2) & 3);
  int arow = m0 + wave * 32 + (lane >> 2);
  int ob = arow >> 11, os = arow & 2047;
  // A = O[b][h][s][d]: row m=(b,s), col k=(h,d); koff(k0)=(k0>>6)*131072+(k0&32)
  const bf16* Asrc = O + (long)ob * 2097152 + (long)os * 64 + schunk * 8;
  const bf16* Bsrc = Bt + (long)(n0 + wave * 16 + (lane >> 2)) * K + schunk * 8;
  int la0 = (wave * 32) * 32;
  int lb0 = (wave * 16) * 32;
  int rdoff = ((quad ^ (col & 3)) << 3);

#define OUT_STAGE(bi, k0n)                                            \
  {                                                                   \
    long ka = ((long)((k0n) >> 6)) * 131072 + ((k0n) & 32);           \
    gload16(Asrc + ka, &As[bi][la0]);                                 \
    gload16(Asrc + ka + 16 * 64, &As[bi][la0 + 16 * 32]);             \
    gload16(Bsrc + (k0n), &Bs[bi][lb0]);                              \
  }

  OUT_STAGE(0, 0);
  __syncthreads();
  for (int k0 = 0; k0 < K; k0 += 32) {
    int cur = (k0 >> 5) & 1;
    if (k0 + 32 < K) OUT_STAGE(cur ^ 1, k0 + 32);
    bfrag ra[4], rb[2];
#pragma unroll
    for (int i = 0; i < 4; ++i)
      ra[i] = *(const bfrag*)(&As[cur][(wr + 16 * i + col) * 32 + rdoff]);
#pragma unroll
    for (int c = 0; c < 2; ++c)
      rb[c] = *(const bfrag*)(&Bs[cur][(wc + 16 * c + col) * 32 + rdoff]);
#pragma unroll
    for (int c = 0; c < 2; ++c)
#pragma unroll
      for (int i = 0; i < 4; ++i) acc[c][i] = MFMA16(ra[i], rb[c], acc[c][i]);
    __syncthreads();
  }
#undef OUT_STAGE

#pragma unroll
  for (int c = 0; c < 2; ++c) {
    int n = n0 + wc + 16 * c + col;
#pragma unroll
    for (int i = 0; i < 4; ++i)
#pragma unroll
      for (int r = 0; r < 4; ++r) {
        int m = m0 + wr + 16 * i + quad * 4 + r;
        Cf[(long)m * 1024 + n] = acc[c][i][r];
      }
  }
}

// ---------------- flash attention: S^T dataflow, 2-barrier pipeline -------
// Q/K head-major [b][h][s][d] (Q pre-scaled); Vt [b][h][d][s]; O head-major.
// S^T = MFMA32(A=K_rows, B=Q_rows): C cols = q (lanes), rows = j (regs).
// p = exp2(s) directly (scale folded into Q; constant bias cancels in lsum).
// P^T feeds PV's B operand via v_permlane32_swap_b32.
// O^T = MFMA32(A=V^T from Vs[d][j], B=P^T): cols = q, rows = d.
// Prefetch loads: wave-uniform base (jn) + constant lane offset.
__global__ __launch_bounds__(256) void attn_kernel(const bf16* __restrict__ Q,
                                                   const bf16* __restrict__ K_,
                                                   const bf16* __restrict__ Vt,
                                                   bf16* __restrict__ O) {
  int id = blockIdx.x;             // 1024 blocks
  int xcd = id & 7, jj = id >> 3;
  int qt = 31 - (jj >> 2);         // LPT
  int bh = ((jj & 3) << 3) | xcd;  // 4 bh per XCD

  __shared__ bf16 Ks[128][72];     // [j][d]; f32 Osc[64][68] overlay in epilogue
  __shared__ bf16 Vs[64][136];     // [d][j]; Lsc + Of overlay in epilogue

  int t = threadIdx.x, wave = t >> 6, lane = t & 63;
  int qh = wave >> 1, jh = wave & 1, hi = lane >> 5, l5 = lane & 31;

  int krow = t >> 3, kg = (t & 7) * 8;
  int vrow = t >> 4, vg = (t & 15) * 8;
  // uniform bases + constant lane offsets for prefetch
  const bf16* KuBase = K_ + (long)bh * 2048 * 64;
  const bf16* VuBase = Vt + (long)bh * 64 * 2048;
  int kL = krow * 64 + kg;         // lane-const
  int vL = vrow * 2048 + vg;       // lane-const

  int q0 = qt * 64;
  int nj = (qt >> 1) + 1;
  int qi = q0 + 32 * qh + l5;      // this lane's global q index

  bfrag qa[4];
  const bf16* qp = Q + ((long)bh * 2048 + q0 + 32 * qh + l5) * 64 + hi * 8;
#pragma unroll
  for (int kd = 0; kd < 4; ++kd) qa[kd] = *(const bfrag*)(qp + kd * 16);

  f32x16 o0, o1;                   // O^T partials: rows d / d+32, col q
  float lsum = 0.f;                // per-lane: sum over this wave's j-half
#pragma unroll
  for (int r = 0; r < 16; ++r) { o0[r] = 0.f; o1[r] = 0.f; }

  // prefetch j-tile 0 (both K and V)
  bfrag kreg[4], vreg[4];
#pragma unroll
  for (int i = 0; i < 4; ++i) {
    kreg[i] = *(const bfrag*)(KuBase + kL + i * 2048);
    vreg[i] = *(const bfrag*)(VuBase + vL + i * 32768);
  }

  for (int jt = 0; jt < nj; ++jt) {
    int j0 = jt * 128;
    __syncthreads();               // prev iter's Ks/Vs reads complete
#pragma unroll
    for (int i = 0; i < 4; ++i) {
      *(bfrag*)(&Ks[krow + 32 * i][kg]) = kreg[i];
      *(bfrag*)(&Vs[vrow + 16 * i][vg]) = vreg[i];
    }
    int jn = (jt + 1 < nj) ? j0 + 128 : j0;       // uniform
    const bf16* kp = KuBase + (long)jn * 64;      // uniform base
    const bf16* vp = VuBase + jn;                 // uniform base
#pragma unroll
    for (int i = 0; i < 4; ++i) {
      kreg[i] = *(const bfrag*)(kp + kL + i * 2048);
      vreg[i] = *(const bfrag*)(vp + vL + i * 32768);
    }
    __syncthreads();               // Ks/Vs ready for all waves

    bool lastT = (jt == nj - 1);
    // even qt: last tile's jh==1 half (j in [q0+64,q0+128)) is fully masked.
    if (lastT && jh == 1 && ((qt & 1) == 0)) continue;

    // S^T: per wave 64j (own half) x 32q. A = K rows, B = Q rows.
    f32x16 s0, s1;
#pragma unroll
    for (int r = 0; r < 16; ++r) { s0[r] = 0.f; s1[r] = 0.f; }
    __builtin_amdgcn_s_setprio(1);
#pragma unroll
    for (int kd = 0; kd < 4; ++kd) {
      bfrag ka0 = *(const bfrag*)(&Ks[jh * 64 + l5][kd * 16 + hi * 8]);
      bfrag ka1 = *(const bfrag*)(&Ks[jh * 64 + 32 + l5][kd * 16 + hi * 8]);
      s0 = MFMA32(ka0, qa[kd], s0);
      s1 = MFMA32(ka1, qa[kd], s1);
    }
    __builtin_amdgcn_s_setprio(0);

    // softmax in-register; pack P^T bf16 groups (g[jb][0..3] = r0-3,4-7,8-11,12-15)
    unsigned g[2][4][2];
#pragma unroll
    for (int jb = 0; jb < 2; ++jb) {
      float pv[16];
      float ls = 0.f;
#pragma unroll
      for (int r = 0; r < 16; ++r) {
        int jl = (r & 3) + 8 * (r >> 2) + 4 * hi;        // j within 32-block
        int j = j0 + jh * 64 + jb * 32 + jl;
        float sv = jb ? s1[r] : s0[r];
        float p = __builtin_amdgcn_exp2f(sv);
        if (lastT) p = (j <= qi) ? p : 0.f;
        ls += p;
        pv[r] = p;
      }
      lsum += ls;
#pragma unroll
      for (int gg = 0; gg < 4; ++gg) {
        g[jb][gg][0] = pk2(pv[4 * gg], pv[4 * gg + 1]);
        g[jb][gg][1] = pk2(pv[4 * gg + 2], pv[4 * gg + 3]);
      }
    }

    // PV: O^T += V^T * P^T over own j-half
    __builtin_amdgcn_s_setprio(1);
#pragma unroll
    for (int jb = 0; jb < 2; ++jb) {
#pragma unroll
      for (int c = 0; c < 2; ++c) {
        // B-frag jj0..7 for k-chunk c: groups 2c (r-lo) and 2c+1 (r-hi).
        unsigned a0 = g[jb][2 * c][0], a1 = g[jb][2 * c][1];
        unsigned b0 = g[jb][2 * c + 1][0], b1 = g[jb][2 * c + 1][1];
        asm("v_permlane32_swap_b32 %0, %1" : "+v"(a0), "+v"(b0));
        asm("v_permlane32_swap_b32 %0, %1" : "+v"(a1), "+v"(b1));
        union { unsigned u[4]; bfrag f; } pf;
        pf.u[0] = a0;
        pf.u[1] = a1;
        pf.u[2] = b0;
        pf.u[3] = b1;
        int kk = jh * 64 + jb * 32 + c * 16 + hi * 8;
        bfrag av0 = *(const bfrag*)(&Vs[l5][kk]);
        bfrag av1 = *(const bfrag*)(&Vs[32 + l5][kk]);
        o0 = MFMA32(av0, pf.f, o0);
        o1 = MFMA32(av1, pf.f, o1);
      }
    }
    __builtin_amdgcn_s_setprio(0);
  }

  // combine hi-halves of lsum (same q, different j-sets)
  lsum += __shfl_xor(lsum, 32, 64);

  __syncthreads();   // all Ks/Vs reads done; overlay scratch
  float* Osc = (float*)&Ks[0][0];                    // [64 q][68 d]
  float* Lsc = (float*)&Vs[0][0];                    // [64 q]
  bf16* Of = (bf16*)((char*)&Vs[0][0] + 512);        // [64 q][72 d]
  int q = 32 * qh + l5;
  if (jh == 1) {
#pragma unroll
    for (int r = 0; r < 16; ++r) {
      int d = (r & 3) + 8 * (r >> 2) + 4 * hi;
      Osc[q * 68 + d] = o0[r];
      Osc[q * 68 + 32 + d] = o1[r];
    }
    if (hi == 0) Lsc[q] = lsum;
  }
  __syncthreads();
  if (jh == 0) {
    float inv = 1.f / (lsum + Lsc[q]);
#pragma unroll
    for (int r = 0; r < 16; ++r) {
      int d = (r & 3) + 8 * (r >> 2) + 4 * hi;
      Of[q * 72 + d] = __float2bfloat16((o0[r] + Osc[q * 68 + d]) * inv);
      Of[q * 72 + 32 + d] = __float2bfloat16((o1[r] + Osc[q * 68 + 32 + d]) * inv);
    }
  }
  __syncthreads();
  int row = t >> 2, off = (t & 3) * 16;
  bf16* po = O + ((long)bh * 2048 + q0 + row) * 64 + off;
  *(bfrag*)(po) = *(const bfrag*)(&Of[row * 72 + off]);
  *(bfrag*)(po + 8) = *(const bfrag*)(&Of[row * 72 + off + 8]);
}

extern "C" void kernel_launch(void* const* d_in, const int* in_sizes, int n_in,
                              void* d_out, int out_size, void* d_ws, size_t ws_size,
                              hipStream_t stream) {
  const float* x  = (const float*)d_in[0];
  const float* Wq = (const float*)d_in[1];
  const float* bq = (const float*)d_in[2];
  const float* Wk = (const float*)d_in[3];
  const float* bk = (const float*)d_in[4];
  const float* Wv = (const float*)d_in[5];
  const float* bv = (const float*)d_in[6];
  const float* Wo = (const float*)d_in[7];
  float* out = (float*)d_out;

  bf16* ws = (bf16*)d_ws;
  const long MB1 = 1 << 20;
  bf16* WqkvT = ws + 0 * MB1;    // [3072][1024]
  bf16* WoT   = ws + 3 * MB1;
  bf16* Q     = ws + 4 * MB1;    // [b][h][s][d]
  bf16* K_    = ws + 8 * MB1;    // [b][h][s][d]
  bf16* Vt    = ws + 12 * MB1;   // [b][h][d][s]
  bf16* O     = ws + 16 * MB1;   // [b][h][s][d]
  bf16* xb    = ws + 20 * MB1;

  prep_all<<<3072, 256, 0, stream>>>(x, Wq, Wk, Wv, Wo, xb, WqkvT, WoT);
  gemm_qkv128<<<768, 256, 0, stream>>>(xb, WqkvT, bq, bk, bv, Q, K_, Vt);
  attn_kernel<<<1024, 256, 0, stream>>>(Q, K_, Vt, O);
  gemm_out<<<512, 256, 0, stream>>>(O, WoT, out);
}

// Round 6
// 192.064 us; speedup vs baseline: 1.0154x; 1.0141x over previous
//
#include <hip/hip_runtime.h>
#include <hip/hip_bf16.h>

// MultiHeadAttention: B=2, S=2048, H=16, D=64, E=1024. f32 I/O, bf16 internal.
// R16 vs R15 (194.8us; gemm_qkv128 top at 49.8us = 516 TF, ALL pipes idle
// (VALU 9%, Mfma 19%, HBM 17%) => 2-phase barrier-drain-bound, the documented
// 2ph regime ceiling):
//  * gemm_qkv128 -> 8-phase 256x256 schedule (T3+T4): BK=64, 8 waves (2Mx4N),
//    128KB dynamic LDS (even/odd-ks buffers), 8KB stage units (2/phase,
//    16/iter), counted s_waitcnt vmcnt(2) ONLY at phases 4 and 8 (never a
//    vmcnt(0) drain in-loop), raw s_barrier pairs around each 16-MFMA cluster,
//    setprio(1) on MFMA (T5). XOR swizzle both-sides: source chunk
//    8*((t&7)^((t>>3)&7)), read offset ^((col&7)<<3) -> uniform 8 req/bank
//    (optimal for b128). Stage targets only regions freed >=1 barrier earlier
//    (race-checked per unit). Grid 192 blocks x 512 thr.
//  * attn / gemm_out / prep: unchanged from R15.

typedef __hip_bfloat16 bf16;
typedef __attribute__((ext_vector_type(8))) short bfrag;    // 8 bf16 = 4 VGPRs
typedef __attribute__((ext_vector_type(4))) float f32x4;
typedef __attribute__((ext_vector_type(16))) float f32x16;  // 32x32 C/D
typedef __attribute__((ext_vector_type(4))) short short4v;

#define MFMA16(a, b, c) __builtin_amdgcn_mfma_f32_16x16x32_bf16(a, b, c, 0, 0, 0)
#define MFMA32(a, b, c) __builtin_amdgcn_mfma_f32_32x32x16_bf16(a, b, c, 0, 0, 0)

__device__ __forceinline__ unsigned pk2(float a, float b) {
  union { __hip_bfloat162 h; unsigned u; } w;
  w.h = __float22bfloat162_rn(make_float2(a, b));
  return w.u;
}

// async global->LDS, 16B per lane; LDS dest = wave-uniform base + lane*16.
__device__ __forceinline__ void gload16(const bf16* g, bf16* l) {
  __builtin_amdgcn_global_load_lds(
      (const __attribute__((address_space(1))) void*)(g),
      (__attribute__((address_space(3))) void*)(l), 16, 0, 0);
}

// raw barrier with compiler memory fences (keep LDS ops from crossing)
__device__ __forceinline__ void barrier_raw() {
  asm volatile("" ::: "memory");
  __builtin_amdgcn_s_barrier();
  asm volatile("" ::: "memory");
}

// ---------------- fused cast + weight transposes --------------------------
// blocks 0..2047: x f32->bf16. 2048..2815: Wq/Wk/Wv -> WqkvT. 2816..3071: Wo.
__global__ __launch_bounds__(256) void prep_all(const float* __restrict__ x,
                                                const float* __restrict__ Wq,
                                                const float* __restrict__ Wk,
                                                const float* __restrict__ Wv,
                                                const float* __restrict__ Wo,
                                                bf16* __restrict__ xb,
                                                bf16* __restrict__ WqkvT,
                                                bf16* __restrict__ WoT) {
  __shared__ bf16 tile[64][80];
  int id = blockIdx.x;
  int t = threadIdx.x;
  if (id < 2048) {
    int i = id * 2048 + t * 8;
    float4 a = *(const float4*)(x + i);
    float4 b = *(const float4*)(x + i + 4);
    union { bf16 h[8]; bfrag v; } tmp;
    tmp.h[0] = __float2bfloat16(a.x); tmp.h[1] = __float2bfloat16(a.y);
    tmp.h[2] = __float2bfloat16(a.z); tmp.h[3] = __float2bfloat16(a.w);
    tmp.h[4] = __float2bfloat16(b.x); tmp.h[5] = __float2bfloat16(b.y);
    tmp.h[6] = __float2bfloat16(b.z); tmp.h[7] = __float2bfloat16(b.w);
    *(bfrag*)(xb + i) = tmp.v;
    return;
  }
  int wid = id - 2048;
  const float* src;
  bf16* dst;
  int srcld, dstld, r0, c0;
  if (wid < 768) {
    int w = wid >> 8, h = (wid >> 4) & 15;
    r0 = (wid & 15) * 64; c0 = 0;
    src = ((w == 0) ? Wq : (w == 1) ? Wk : Wv) + (long)h * 1024 * 64;
    dst = WqkvT + ((long)w * 1024 + h * 64) * 1024;
    srcld = 64; dstld = 1024;
  } else {
    int j = wid - 768;
    c0 = (j & 15) * 64; r0 = (j >> 4) * 64;
    src = Wo; dst = WoT;
    srcld = 1024; dstld = 1024;
  }
  int lr = t >> 3, lc = (t & 7) << 3;
#pragma unroll
  for (int p = 0; p < 2; ++p) {
    int r = lr + p * 32;
    const float* s = src + (long)(r0 + r) * srcld + c0 + lc;
    union { bf16 h8[8]; bfrag v; } tmp;
#pragma unroll
    for (int j = 0; j < 8; ++j) tmp.h8[j] = __float2bfloat16(s[j]);
    *(bfrag*)(&tile[r][lc]) = tmp.v;
  }
  __syncthreads();
#pragma unroll
  for (int p = 0; p < 2; ++p) {
    int c = lr + p * 32;
    union { bf16 h8[8]; bfrag v; } tmp;
#pragma unroll
    for (int j = 0; j < 8; ++j) tmp.h8[j] = tile[lc + j][c];
    *(bfrag*)(dst + (long)(c0 + c) * dstld + r0 + lc) = tmp.v;
  }
}

// ---------------- fused QKV GEMM: 256x256, BK=64, 8-phase counted-vmcnt ---
// C[4096][3072] = xb[4096][1024] . WT[3072][1024]^T.
// 512 threads = 8 waves (wm=wave>>2, wn=wave&3); per-wave C = 128x64.
// LDS (dynamic 128KB, bf16 elems):
//   A: [buf(par ks)][half][128 rows][64 k] at  buf*16384 + half*8192
//   B: same at +32768.
// Stage unit = 8KB = 64 rows x 64 k of one half (1 gload16/thread).
// Swizzle: slot s of row r holds chunk s^(r&7); src chunk lane-const.
// Phase p computes (ks, mh, kc): 4 A-frags x 4 B-frags x 16 MFMA16.
// Stage placement (race-free; regions freed >=1 barrier before stage):
//   p1: buf1 A-g1 (ks=2it+1)   p2: buf1 B-h0   p3: buf1 B-h1
//   p4: buf0 A-g0 (ks=2it+2)   p5: buf0 A-g1   p6: buf0 B-h0  p7: buf0 B-h1
//   p8: buf1 A-g0 (ks=2it+3)
// vmcnt(2) at end of p4 (buf1 ready for p5) and p8 (buf0 ready for next p1).
__global__ __launch_bounds__(512, 2) void gemm_qkv128(const bf16* __restrict__ xb,
                                                      const bf16* __restrict__ WT,
                                                      const float* __restrict__ bq,
                                                      const float* __restrict__ bk,
                                                      const float* __restrict__ bv,
                                                      bf16* __restrict__ Q,
                                                      bf16* __restrict__ K_,
                                                      bf16* __restrict__ Vt) {
  extern __shared__ bf16 lds[];
  int id = blockIdx.x;
  int xcd = id & 7, idx = id >> 3;
  int tile = xcd * 24 + idx;          // 192 = 16 mt x 12 nt, bijective
  int mt = tile & 15, nt = tile >> 4;
  int m0 = mt * 256, n0 = nt * 256;

  int t = threadIdx.x;
  int wave = t >> 6, lane = t & 63, quad = lane >> 4, col = lane & 15;
  int wm = wave >> 2, wn = wave & 3;

  // staging addresses
  int schunk = 8 * ((t & 7) ^ ((t >> 3) & 7));   // pre-swizzled source chunk
  const bf16* aSrc = xb + (long)(m0 + (t >> 3)) * 1024 + schunk;
  const bf16* bSrc = WT + (long)(n0 + (t >> 3)) * 1024 + schunk;
  int wv512 = wave * 512;                         // wave-uniform LDS sub-base

  // read addresses (element offsets); xoff kc=1 = xoff0 ^ 32
  int xoff0 = (quad * 8) ^ ((col & 7) << 3);
  const bf16* aRdB = lds + wm * 8192 + col * 64;
  const bf16* bRdB = lds + 32768 + (wn >> 1) * 8192 + (wn & 1) * 4096 + col * 64;

  f32x4 acc[8][4] = {};

#define STA(BUF, HALF, G, KS)                                                  \
  gload16(aSrc + (long)((HALF)*128 + (G)*64) * 1024 + (KS)*64,                 \
          lds + (BUF)*16384 + (HALF)*8192 + (G)*4096 + wv512)
#define STB(BUF, HALF, G, KS)                                                  \
  gload16(bSrc + (long)((HALF)*128 + (G)*64) * 1024 + (KS)*64,                 \
          lds + 32768 + (BUF)*16384 + (HALF)*8192 + (G)*4096 + wv512)

#define PHASE(BUF, MH, KC, STAGES, VMW)                                        \
  {                                                                            \
    int xk = xoff0 ^ ((KC)*32);                                                \
    bfrag ra[4], rb[4];                                                        \
    _Pragma("unroll") for (int u = 0; u < 4; ++u) {                            \
      ra[u] = *(const bfrag*)(aRdB + (BUF)*16384 + (MH)*4096 + u * 1024 + xk); \
      rb[u] = *(const bfrag*)(bRdB + (BUF)*16384 + u * 1024 + xk);             \
    }                                                                          \
    STAGES;                                                                    \
    VMW;                                                                       \
    barrier_raw();                                                             \
    __builtin_amdgcn_s_setprio(1);                                             \
    _Pragma("unroll") for (int ni = 0; ni < 4; ++ni)                           \
      _Pragma("unroll") for (int mi2 = 0; mi2 < 4; ++mi2)                      \
        acc[(MH)*4 + mi2][ni] = MFMA16(ra[mi2], rb[ni], acc[(MH)*4 + mi2][ni]);\
    __builtin_amdgcn_s_setprio(0);                                             \
    barrier_raw();                                                             \
  }

#define VM2 asm volatile("s_waitcnt vmcnt(2)" ::: "memory")
#define NOVM

  // prologue: buf0 <- ks0 (8 units), buf1 A-g0 <- ks1 (mimics steady p8)
  STA(0, 0, 0, 0); STA(0, 1, 0, 0); STA(0, 0, 1, 0); STA(0, 1, 1, 0);
  STB(0, 0, 0, 0); STB(0, 0, 1, 0); STB(0, 1, 0, 0); STB(0, 1, 1, 0);
  STA(1, 0, 0, 1); STA(1, 1, 0, 1);
  VM2;
  barrier_raw();

  for (int it = 0; it < 8; ++it) {
    int ksB = 2 * it + 1;                         // buf1 content, used p5-8
    int kA  = (it < 7) ? 2 * it + 2 : 14;         // buf0 next content (clamped)
    int ksB2 = (it < 7) ? 2 * it + 3 : 15;        // buf1 next content (clamped)
    PHASE(0, 0, 0, { STA(1, 0, 1, ksB); STA(1, 1, 1, ksB); }, NOVM);   // p1
    PHASE(0, 0, 1, { STB(1, 0, 0, ksB); STB(1, 0, 1, ksB); }, NOVM);   // p2
    PHASE(0, 1, 0, { STB(1, 1, 0, ksB); STB(1, 1, 1, ksB); }, NOVM);   // p3
    PHASE(0, 1, 1, { STA(0, 0, 0, kA); STA(0, 1, 0, kA); }, VM2);      // p4
    PHASE(1, 0, 0, { STA(0, 0, 1, kA); STA(0, 1, 1, kA); }, NOVM);     // p5
    PHASE(1, 0, 1, { STB(0, 0, 0, kA); STB(0, 0, 1, kA); }, NOVM);     // p6
    PHASE(1, 1, 0, { STB(0, 1, 0, kA); STB(0, 1, 1, kA); }, NOVM);     // p7
    PHASE(1, 1, 1, { STA(1, 0, 0, ksB2); STA(1, 1, 0, ksB2); }, VM2);  // p8
  }
#undef PHASE
#undef STA
#undef STB
#undef VM2
#undef NOVM

  int sel = n0 >> 10;   // 0=Q, 1=K, 2=V (256-tiles never cross 1024 boundary)
  const float* bias = (sel == 0) ? bq : (sel == 1) ? bk : bv;
  float qs = (sel == 0) ? 0.18033688f : 1.0f;   // (1/8)*log2(e) folded into Q
#pragma unroll
  for (int ni = 0; ni < 4; ++ni) {
    int nn = (n0 + wn * 64 + ni * 16 + col) & 1023;
    float bvv = bias[nn];
    int h = nn >> 6, d = nn & 63;
#pragma unroll
    for (int mi = 0; mi < 8; ++mi) {
      int mb = m0 + wm * 128 + mi * 16 + quad * 4;
      int b = mb >> 11, s0q = mb & 2047;
      if (sel < 2) {
        bf16* dst = (sel == 0) ? Q : K_;
        long base = ((long)((b << 4) + h) * 2048 + s0q) * 64 + d;
#pragma unroll
        for (int r = 0; r < 4; ++r)
          dst[base + (long)r * 64] = __float2bfloat16((acc[mi][ni][r] + bvv) * qs);
      } else {
        union { bf16 h4[4]; short4v v; } pk;
#pragma unroll
        for (int r = 0; r < 4; ++r) pk.h4[r] = __float2bfloat16(acc[mi][ni][r] + bvv);
        *(short4v*)(Vt + (long)(((b << 4) + h) * 64 + d) * 2048 + s0q) = pk.v;
      }
    }
  }
}

// ---------------- out-projection: 128x64, BK=32, gload_lds dbuf -----------
__global__ __launch_bounds__(256) void gemm_out(const bf16* __restrict__ O,
                                                const bf16* __restrict__ Bt,
                                                float* __restrict__ Cf) {
  const int K = 1024;
  __shared__ bf16 As[2][128 * 32];
  __shared__ bf16 Bs[2][64 * 32];
  int id = blockIdx.x;
  int xcd = id & 7, sw = id >> 3;
  int m0 = ((xcd << 2) | (sw & 3)) * 128;
  int n0 = (sw >> 2) * 64;
  int t = threadIdx.x;
  int wave = t >> 6, lane = t & 63, quad = lane >> 4, col = lane & 15;
  int wr = (wave >> 1) * 64, wc = (wave & 1) * 32;
  f32x4 acc[2][4] = {};

  int schunk = (lane & 3) ^ ((lane >> 2) & 3);
  int arow = m0 + wave * 32 + (lane >> 2);
  int ob = arow >> 11, os = arow & 2047;
  const bf16* Asrc = O + (long)ob * 2097152 + (long)os * 64 + schunk * 8;
  const bf16* Bsrc = Bt + (long)(n0 + wave * 16 + (lane >> 2)) * K + schunk * 8;
  int la0 = (wave * 32) * 32;
  int lb0 = (wave * 16) * 32;
  int rdoff = ((quad ^ (col & 3)) << 3);

#define OUT_STAGE(bi, k0n)                                            \
  {                                                                   \
    long ka = ((long)((k0n) >> 6)) * 131072 + ((k0n) & 32);           \
    gload16(Asrc + ka, &As[bi][la0]);                                 \
    gload16(Asrc + ka + 16 * 64, &As[bi][la0 + 16 * 32]);             \
    gload16(Bsrc + (k0n), &Bs[bi][lb0]);                              \
  }

  OUT_STAGE(0, 0);
  __syncthreads();
  for (int k0 = 0; k0 < K; k0 += 32) {
    int cur = (k0 >> 5) & 1;
    if (k0 + 32 < K) OUT_STAGE(cur ^ 1, k0 + 32);
    bfrag ra[4], rb[2];
#pragma unroll
    for (int i = 0; i < 4; ++i)
      ra[i] = *(const bfrag*)(&As[cur][(wr + 16 * i + col) * 32 + rdoff]);
#pragma unroll
    for (int c = 0; c < 2; ++c)
      rb[c] = *(const bfrag*)(&Bs[cur][(wc + 16 * c + col) * 32 + rdoff]);
#pragma unroll
    for (int c = 0; c < 2; ++c)
#pragma unroll
      for (int i = 0; i < 4; ++i) acc[c][i] = MFMA16(ra[i], rb[c], acc[c][i]);
    __syncthreads();
  }
#undef OUT_STAGE

#pragma unroll
  for (int c = 0; c < 2; ++c) {
    int n = n0 + wc + 16 * c + col;
#pragma unroll
    for (int i = 0; i < 4; ++i)
#pragma unroll
      for (int r = 0; r < 4; ++r) {
        int m = m0 + wr + 16 * i + quad * 4 + r;
        Cf[(long)m * 1024 + n] = acc[c][i][r];
      }
  }
}

// ---------------- flash attention: S^T dataflow, 2-barrier pipeline -------
// Q/K head-major [b][h][s][d] (Q pre-scaled); Vt [b][h][d][s]; O head-major.
// S^T = MFMA32(A=K_rows, B=Q_rows): C cols = q (lanes), rows = j (regs).
// p = exp2(s) directly (scale folded into Q; constant bias cancels in lsum).
// P^T feeds PV's B operand via v_permlane32_swap_b32.
// O^T = MFMA32(A=V^T from Vs[d][j], B=P^T): cols = q, rows = d.
// Prefetch loads: wave-uniform base (jn) + constant lane offset.
__global__ __launch_bounds__(256) void attn_kernel(const bf16* __restrict__ Q,
                                                   const bf16* __restrict__ K_,
                                                   const bf16* __restrict__ Vt,
                                                   bf16* __restrict__ O) {
  int id = blockIdx.x;             // 1024 blocks
  int xcd = id & 7, jj = id >> 3;
  int qt = 31 - (jj >> 2);         // LPT
  int bh = ((jj & 3) << 3) | xcd;  // 4 bh per XCD

  __shared__ bf16 Ks[128][72];     // [j][d]; f32 Osc[64][68] overlay in epilogue
  __shared__ bf16 Vs[64][136];     // [d][j]; Lsc + Of overlay in epilogue

  int t = threadIdx.x, wave = t >> 6, lane = t & 63;
  int qh = wave >> 1, jh = wave & 1, hi = lane >> 5, l5 = lane & 31;

  int krow = t >> 3, kg = (t & 7) * 8;
  int vrow = t >> 4, vg = (t & 15) * 8;
  // uniform bases + constant lane offsets for prefetch
  const bf16* KuBase = K_ + (long)bh * 2048 * 64;
  const bf16* VuBase = Vt + (long)bh * 64 * 2048;
  int kL = krow * 64 + kg;         // lane-const
  int vL = vrow * 2048 + vg;       // lane-const

  int q0 = qt * 64;
  int nj = (qt >> 1) + 1;
  int qi = q0 + 32 * qh + l5;      // this lane's global q index

  bfrag qa[4];
  const bf16* qp = Q + ((long)bh * 2048 + q0 + 32 * qh + l5) * 64 + hi * 8;
#pragma unroll
  for (int kd = 0; kd < 4; ++kd) qa[kd] = *(const bfrag*)(qp + kd * 16);

  f32x16 o0, o1;                   // O^T partials: rows d / d+32, col q
  float lsum = 0.f;                // per-lane: sum over this wave's j-half
#pragma unroll
  for (int r = 0; r < 16; ++r) { o0[r] = 0.f; o1[r] = 0.f; }

  // prefetch j-tile 0 (both K and V)
  bfrag kreg[4], vreg[4];
#pragma unroll
  for (int i = 0; i < 4; ++i) {
    kreg[i] = *(const bfrag*)(KuBase + kL + i * 2048);
    vreg[i] = *(const bfrag*)(VuBase + vL + i * 32768);
  }

  for (int jt = 0; jt < nj; ++jt) {
    int j0 = jt * 128;
    __syncthreads();               // prev iter's Ks/Vs reads complete
#pragma unroll
    for (int i = 0; i < 4; ++i) {
      *(bfrag*)(&Ks[krow + 32 * i][kg]) = kreg[i];
      *(bfrag*)(&Vs[vrow + 16 * i][vg]) = vreg[i];
    }
    int jn = (jt + 1 < nj) ? j0 + 128 : j0;       // uniform
    const bf16* kp = KuBase + (long)jn * 64;      // uniform base
    const bf16* vp = VuBase + jn;                 // uniform base
#pragma unroll
    for (int i = 0; i < 4; ++i) {
      kreg[i] = *(const bfrag*)(kp + kL + i * 2048);
      vreg[i] = *(const bfrag*)(vp + vL + i * 32768);
    }
    __syncthreads();               // Ks/Vs ready for all waves

    bool lastT = (jt == nj - 1);
    // even qt: last tile's jh==1 half (j in [q0+64,q0+128)) is fully masked.
    if (lastT && jh == 1 && ((qt & 1) == 0)) continue;

    // S^T: per wave 64j (own half) x 32q. A = K rows, B = Q rows.
    f32x16 s0, s1;
#pragma unroll
    for (int r = 0; r < 16; ++r) { s0[r] = 0.f; s1[r] = 0.f; }
    __builtin_amdgcn_s_setprio(1);
#pragma unroll
    for (int kd = 0; kd < 4; ++kd) {
      bfrag ka0 = *(const bfrag*)(&Ks[jh * 64 + l5][kd * 16 + hi * 8]);
      bfrag ka1 = *(const bfrag*)(&Ks[jh * 64 + 32 + l5][kd * 16 + hi * 8]);
      s0 = MFMA32(ka0, qa[kd], s0);
      s1 = MFMA32(ka1, qa[kd], s1);
    }
    __builtin_amdgcn_s_setprio(0);

    // softmax in-register; pack P^T bf16 groups (g[jb][0..3] = r0-3,4-7,8-11,12-15)
    unsigned g[2][4][2];
#pragma unroll
    for (int jb = 0; jb < 2; ++jb) {
      float pv[16];
      float ls = 0.f;
#pragma unroll
      for (int r = 0; r < 16; ++r) {
        int jl = (r & 3) + 8 * (r >> 2) + 4 * hi;        // j within 32-block
        int j = j0 + jh * 64 + jb * 32 + jl;
        float sv = jb ? s1[r] : s0[r];
        float p = __builtin_amdgcn_exp2f(sv);
        if (lastT) p = (j <= qi) ? p : 0.f;
        ls += p;
        pv[r] = p;
      }
      lsum += ls;
#pragma unroll
      for (int gg = 0; gg < 4; ++gg) {
        g[jb][gg][0] = pk2(pv[4 * gg], pv[4 * gg + 1]);
        g[jb][gg][1] = pk2(pv[4 * gg + 2], pv[4 * gg + 3]);
      }
    }

    // PV: O^T += V^T * P^T over own j-half
    __builtin_amdgcn_s_setprio(1);
#pragma unroll
    for (int jb = 0; jb < 2; ++jb) {
#pragma unroll
      for (int c = 0; c < 2; ++c) {
        // B-frag jj0..7 for k-chunk c: groups 2c (r-lo) and 2c+1 (r-hi).
        unsigned a0 = g[jb][2 * c][0], a1 = g[jb][2 * c][1];
        unsigned b0 = g[jb][2 * c + 1][0], b1 = g[jb][2 * c + 1][1];
        asm("v_permlane32_swap_b32 %0, %1" : "+v"(a0), "+v"(b0));
        asm("v_permlane32_swap_b32 %0, %1" : "+v"(a1), "+v"(b1));
        union { unsigned u[4]; bfrag f; } pf;
        pf.u[0] = a0;
        pf.u[1] = a1;
        pf.u[2] = b0;
        pf.u[3] = b1;
        int kk = jh * 64 + jb * 32 + c * 16 + hi * 8;
        bfrag av0 = *(const bfrag*)(&Vs[l5][kk]);
        bfrag av1 = *(const bfrag*)(&Vs[32 + l5][kk]);
        o0 = MFMA32(av0, pf.f, o0);
        o1 = MFMA32(av1, pf.f, o1);
      }
    }
    __builtin_amdgcn_s_setprio(0);
  }

  // combine hi-halves of lsum (same q, different j-sets)
  lsum += __shfl_xor(lsum, 32, 64);

  __syncthreads();   // all Ks/Vs reads done; overlay scratch
  float* Osc = (float*)&Ks[0][0];                    // [64 q][68 d]
  float* Lsc = (float*)&Vs[0][0];                    // [64 q]
  bf16* Of = (bf16*)((char*)&Vs[0][0] + 512);        // [64 q][72 d]
  int q = 32 * qh + l5;
  if (jh == 1) {
#pragma unroll
    for (int r = 0; r < 16; ++r) {
      int d = (r & 3) + 8 * (r >> 2) + 4 * hi;
      Osc[q * 68 + d] = o0[r];
      Osc[q * 68 + 32 + d] = o1[r];
    }
    if (hi == 0) Lsc[q] = lsum;
  }
  __syncthreads();
  if (jh == 0) {
    float inv = 1.f / (lsum + Lsc[q]);
#pragma unroll
    for (int r = 0; r < 16; ++r) {
      int d = (r & 3) + 8 * (r >> 2) + 4 * hi;
      Of[q * 72 + d] = __float2bfloat16((o0[r] + Osc[q * 68 + d]) * inv);
      Of[q * 72 + 32 + d] = __float2bfloat16((o1[r] + Osc[q * 68 + 32 + d]) * inv);
    }
  }
  __syncthreads();
  int row = t >> 2, off = (t & 3) * 16;
  bf16* po = O + ((long)bh * 2048 + q0 + row) * 64 + off;
  *(bfrag*)(po) = *(const bfrag*)(&Of[row * 72 + off]);
  *(bfrag*)(po + 8) = *(const bfrag*)(&Of[row * 72 + off + 8]);
}

extern "C" void kernel_launch(void* const* d_in, const int* in_sizes, int n_in,
                              void* d_out, int out_size, void* d_ws, size_t ws_size,
                              hipStream_t stream) {
  const float* x  = (const float*)d_in[0];
  const float* Wq = (const float*)d_in[1];
  const float* bq = (const float*)d_in[2];
  const float* Wk = (const float*)d_in[3];
  const float* bk = (const float*)d_in[4];
  const float* Wv = (const float*)d_in[5];
  const float* bv = (const float*)d_in[6];
  const float* Wo = (const float*)d_in[7];
  float* out = (float*)d_out;

  bf16* ws = (bf16*)d_ws;
  const long MB1 = 1 << 20;
  bf16* WqkvT = ws + 0 * MB1;    // [3072][1024]
  bf16* WoT   = ws + 3 * MB1;
  bf16* Q     = ws + 4 * MB1;    // [b][h][s][d]
  bf16* K_    = ws + 8 * MB1;    // [b][h][s][d]
  bf16* Vt    = ws + 12 * MB1;   // [b][h][d][s]
  bf16* O     = ws + 16 * MB1;   // [b][h][s][d]
  bf16* xb    = ws + 20 * MB1;

  prep_all<<<3072, 256, 0, stream>>>(x, Wq, Wk, Wv, Wo, xb, WqkvT, WoT);
  gemm_qkv128<<<192, 512, 131072, stream>>>(xb, WqkvT, bq, bk, bv, Q, K_, Vt);
  attn_kernel<<<1024, 256, 0, stream>>>(Q, K_, Vt, O);
  gemm_out<<<512, 256, 0, stream>>>(O, WoT, out);
}

// Round 7
// 188.961 us; speedup vs baseline: 1.0320x; 1.0164x over previous
//
#include <hip/hip_runtime.h>
#include <hip/hip_bf16.h>

// MultiHeadAttention: B=2, S=2048, H=16, D=64, E=1024. f32 I/O, bf16 internal.
// R17 vs R16 (192.1us; qkv 44.2us with WRITE 46MB vs 25 ideal + FETCH 37MB vs
// 15 => scalar-bf16 direct-store epilogue causes sector RMW; ~15-20us of the
// kernel is write-bound):
//  * gemm_qkv: LDS-staged epilogue. After K-loop: vmcnt(0)+barrier, reuse LDS
//    as 256x[264] bf16 tile. Q/K: [m][n] stage (scalar b16 writes, 2-way max)
//    -> per-thread 16B bfrag stores, 16 passes; every 8-lane cluster = one
//    full 128B head-row (no partial lines). V: transposed [n][m] stage (32 x
//    ds_write_b64 of cvt_pk pairs) -> LDS rows == Vt rows, same store loop.
//    LDS alloc 131072 -> 135168 (still 1 block/CU).
//  * K-loop (8-phase counted-vmcnt), attn, gemm_out, prep: unchanged.

typedef __hip_bfloat16 bf16;
typedef __attribute__((ext_vector_type(8))) short bfrag;    // 8 bf16 = 4 VGPRs
typedef __attribute__((ext_vector_type(4))) float f32x4;
typedef __attribute__((ext_vector_type(16))) float f32x16;  // 32x32 C/D
typedef __attribute__((ext_vector_type(4))) short short4v;

#define MFMA16(a, b, c) __builtin_amdgcn_mfma_f32_16x16x32_bf16(a, b, c, 0, 0, 0)
#define MFMA32(a, b, c) __builtin_amdgcn_mfma_f32_32x32x16_bf16(a, b, c, 0, 0, 0)

__device__ __forceinline__ unsigned pk2(float a, float b) {
  union { __hip_bfloat162 h; unsigned u; } w;
  w.h = __float22bfloat162_rn(make_float2(a, b));
  return w.u;
}

// async global->LDS, 16B per lane; LDS dest = wave-uniform base + lane*16.
__device__ __forceinline__ void gload16(const bf16* g, bf16* l) {
  __builtin_amdgcn_global_load_lds(
      (const __attribute__((address_space(1))) void*)(g),
      (__attribute__((address_space(3))) void*)(l), 16, 0, 0);
}

// raw barrier with compiler memory fences (keep LDS ops from crossing)
__device__ __forceinline__ void barrier_raw() {
  asm volatile("" ::: "memory");
  __builtin_amdgcn_s_barrier();
  asm volatile("" ::: "memory");
}

// ---------------- fused cast + weight transposes --------------------------
// blocks 0..2047: x f32->bf16. 2048..2815: Wq/Wk/Wv -> WqkvT. 2816..3071: Wo.
__global__ __launch_bounds__(256) void prep_all(const float* __restrict__ x,
                                                const float* __restrict__ Wq,
                                                const float* __restrict__ Wk,
                                                const float* __restrict__ Wv,
                                                const float* __restrict__ Wo,
                                                bf16* __restrict__ xb,
                                                bf16* __restrict__ WqkvT,
                                                bf16* __restrict__ WoT) {
  __shared__ bf16 tile[64][80];
  int id = blockIdx.x;
  int t = threadIdx.x;
  if (id < 2048) {
    int i = id * 2048 + t * 8;
    float4 a = *(const float4*)(x + i);
    float4 b = *(const float4*)(x + i + 4);
    union { bf16 h[8]; bfrag v; } tmp;
    tmp.h[0] = __float2bfloat16(a.x); tmp.h[1] = __float2bfloat16(a.y);
    tmp.h[2] = __float2bfloat16(a.z); tmp.h[3] = __float2bfloat16(a.w);
    tmp.h[4] = __float2bfloat16(b.x); tmp.h[5] = __float2bfloat16(b.y);
    tmp.h[6] = __float2bfloat16(b.z); tmp.h[7] = __float2bfloat16(b.w);
    *(bfrag*)(xb + i) = tmp.v;
    return;
  }
  int wid = id - 2048;
  const float* src;
  bf16* dst;
  int srcld, dstld, r0, c0;
  if (wid < 768) {
    int w = wid >> 8, h = (wid >> 4) & 15;
    r0 = (wid & 15) * 64; c0 = 0;
    src = ((w == 0) ? Wq : (w == 1) ? Wk : Wv) + (long)h * 1024 * 64;
    dst = WqkvT + ((long)w * 1024 + h * 64) * 1024;
    srcld = 64; dstld = 1024;
  } else {
    int j = wid - 768;
    c0 = (j & 15) * 64; r0 = (j >> 4) * 64;
    src = Wo; dst = WoT;
    srcld = 1024; dstld = 1024;
  }
  int lr = t >> 3, lc = (t & 7) << 3;
#pragma unroll
  for (int p = 0; p < 2; ++p) {
    int r = lr + p * 32;
    const float* s = src + (long)(r0 + r) * srcld + c0 + lc;
    union { bf16 h8[8]; bfrag v; } tmp;
#pragma unroll
    for (int j = 0; j < 8; ++j) tmp.h8[j] = __float2bfloat16(s[j]);
    *(bfrag*)(&tile[r][lc]) = tmp.v;
  }
  __syncthreads();
#pragma unroll
  for (int p = 0; p < 2; ++p) {
    int c = lr + p * 32;
    union { bf16 h8[8]; bfrag v; } tmp;
#pragma unroll
    for (int j = 0; j < 8; ++j) tmp.h8[j] = tile[lc + j][c];
    *(bfrag*)(dst + (long)(c0 + c) * dstld + r0 + lc) = tmp.v;
  }
}

// ---------------- fused QKV GEMM: 256x256, BK=64, 8-phase counted-vmcnt ---
// C[4096][3072] = xb[4096][1024] . WT[3072][1024]^T.
// 512 threads = 8 waves (wm=wave>>2, wn=wave&3); per-wave C = 128x64.
// LDS (dynamic 135168B): k-loop uses first 128KB as A/B double buffers;
// epilogue reuses it as a 256x[264] bf16 output tile.
// Stage unit = 8KB; swizzle: slot s of row r holds chunk s^(r&7).
// vmcnt(2) only at phases 4 and 8 (counted, never 0 in-loop).
__global__ __launch_bounds__(512, 2) void gemm_qkv128(const bf16* __restrict__ xb,
                                                      const bf16* __restrict__ WT,
                                                      const float* __restrict__ bq,
                                                      const float* __restrict__ bk,
                                                      const float* __restrict__ bv,
                                                      bf16* __restrict__ Q,
                                                      bf16* __restrict__ K_,
                                                      bf16* __restrict__ Vt) {
  extern __shared__ bf16 lds[];
  int id = blockIdx.x;
  int xcd = id & 7, idx = id >> 3;
  int tile = xcd * 24 + idx;          // 192 = 16 mt x 12 nt, bijective
  int mt = tile & 15, nt = tile >> 4;
  int m0 = mt * 256, n0 = nt * 256;

  int t = threadIdx.x;
  int wave = t >> 6, lane = t & 63, quad = lane >> 4, col = lane & 15;
  int wm = wave >> 2, wn = wave & 3;

  // staging addresses
  int schunk = 8 * ((t & 7) ^ ((t >> 3) & 7));   // pre-swizzled source chunk
  const bf16* aSrc = xb + (long)(m0 + (t >> 3)) * 1024 + schunk;
  const bf16* bSrc = WT + (long)(n0 + (t >> 3)) * 1024 + schunk;
  int wv512 = wave * 512;                         // wave-uniform LDS sub-base

  // read addresses (element offsets); xoff kc=1 = xoff0 ^ 32
  int xoff0 = (quad * 8) ^ ((col & 7) << 3);
  const bf16* aRdB = lds + wm * 8192 + col * 64;
  const bf16* bRdB = lds + 32768 + (wn >> 1) * 8192 + (wn & 1) * 4096 + col * 64;

  f32x4 acc[8][4] = {};

#define STA(BUF, HALF, G, KS)                                                  \
  gload16(aSrc + (long)((HALF)*128 + (G)*64) * 1024 + (KS)*64,                 \
          lds + (BUF)*16384 + (HALF)*8192 + (G)*4096 + wv512)
#define STB(BUF, HALF, G, KS)                                                  \
  gload16(bSrc + (long)((HALF)*128 + (G)*64) * 1024 + (KS)*64,                 \
          lds + 32768 + (BUF)*16384 + (HALF)*8192 + (G)*4096 + wv512)

#define PHASE(BUF, MH, KC, STAGES, VMW)                                        \
  {                                                                            \
    int xk = xoff0 ^ ((KC)*32);                                                \
    bfrag ra[4], rb[4];                                                        \
    _Pragma("unroll") for (int u = 0; u < 4; ++u) {                            \
      ra[u] = *(const bfrag*)(aRdB + (BUF)*16384 + (MH)*4096 + u * 1024 + xk); \
      rb[u] = *(const bfrag*)(bRdB + (BUF)*16384 + u * 1024 + xk);             \
    }                                                                          \
    STAGES;                                                                    \
    VMW;                                                                       \
    barrier_raw();                                                             \
    __builtin_amdgcn_s_setprio(1);                                             \
    _Pragma("unroll") for (int ni = 0; ni < 4; ++ni)                           \
      _Pragma("unroll") for (int mi2 = 0; mi2 < 4; ++mi2)                      \
        acc[(MH)*4 + mi2][ni] = MFMA16(ra[mi2], rb[ni], acc[(MH)*4 + mi2][ni]);\
    __builtin_amdgcn_s_setprio(0);                                             \
    barrier_raw();                                                             \
  }

#define VM2 asm volatile("s_waitcnt vmcnt(2)" ::: "memory")
#define NOVM

  // prologue: buf0 <- ks0 (8 units), buf1 A-g0 <- ks1 (mimics steady p8)
  STA(0, 0, 0, 0); STA(0, 1, 0, 0); STA(0, 0, 1, 0); STA(0, 1, 1, 0);
  STB(0, 0, 0, 0); STB(0, 0, 1, 0); STB(0, 1, 0, 0); STB(0, 1, 1, 0);
  STA(1, 0, 0, 1); STA(1, 1, 0, 1);
  VM2;
  barrier_raw();

  for (int it = 0; it < 8; ++it) {
    int ksB = 2 * it + 1;                         // buf1 content, used p5-8
    int kA  = (it < 7) ? 2 * it + 2 : 14;         // buf0 next content (clamped)
    int ksB2 = (it < 7) ? 2 * it + 3 : 15;        // buf1 next content (clamped)
    PHASE(0, 0, 0, { STA(1, 0, 1, ksB); STA(1, 1, 1, ksB); }, NOVM);   // p1
    PHASE(0, 0, 1, { STB(1, 0, 0, ksB); STB(1, 0, 1, ksB); }, NOVM);   // p2
    PHASE(0, 1, 0, { STB(1, 1, 0, ksB); STB(1, 1, 1, ksB); }, NOVM);   // p3
    PHASE(0, 1, 1, { STA(0, 0, 0, kA); STA(0, 1, 0, kA); }, VM2);      // p4
    PHASE(1, 0, 0, { STA(0, 0, 1, kA); STA(0, 1, 1, kA); }, NOVM);     // p5
    PHASE(1, 0, 1, { STB(0, 0, 0, kA); STB(0, 0, 1, kA); }, NOVM);     // p6
    PHASE(1, 1, 0, { STB(0, 1, 0, kA); STB(0, 1, 1, kA); }, NOVM);     // p7
    PHASE(1, 1, 1, { STA(1, 0, 0, ksB2); STA(1, 1, 0, ksB2); }, VM2);  // p8
  }
#undef PHASE
#undef STA
#undef STB
#undef VM2
#undef NOVM

  // ---- epilogue: drain stray prefetches, repurpose LDS as output tile ----
  asm volatile("s_waitcnt vmcnt(0)" ::: "memory");
  barrier_raw();

  int sel = n0 >> 10;   // 0=Q, 1=K, 2=V (256-tiles never cross 1024 boundary)
  const float* bias = (sel == 0) ? bq : (sel == 1) ? bk : bv;
  float qs = (sel == 0) ? 0.18033688f : 1.0f;   // (1/8)*log2(e) folded into Q
  int b = m0 >> 11, sbase = m0 & 2047, nq = n0 & 1023;
  int seg = (t & 31) * 8;

  if (sel < 2) {
    // stage [m][264 n]
#pragma unroll
    for (int ni = 0; ni < 4; ++ni) {
      int n = wn * 64 + ni * 16 + col;
      float bvv = bias[nq + n];
#pragma unroll
      for (int mi = 0; mi < 8; ++mi) {
        int mrow = wm * 128 + mi * 16 + quad * 4;
#pragma unroll
        for (int r = 0; r < 4; ++r)
          lds[(mrow + r) * 264 + n] = __float2bfloat16((acc[mi][ni][r] + bvv) * qs);
      }
    }
    barrier_raw();
    bf16* dst = (sel == 0) ? Q : K_;
    int h = (nq + seg) >> 6, d = seg & 63;
    long gb = ((long)((b << 4) + h) * 2048 + sbase) * 64 + d;
#pragma unroll
    for (int p = 0; p < 16; ++p) {
      int row = (t >> 5) + p * 16;
      *(bfrag*)(dst + gb + (long)row * 64) = *(const bfrag*)(lds + row * 264 + seg);
    }
  } else {
    // stage transposed [n][264 m] with packed b64 writes
#pragma unroll
    for (int ni = 0; ni < 4; ++ni) {
      int n = wn * 64 + ni * 16 + col;
      float bvv = bias[nq + n];
#pragma unroll
      for (int mi = 0; mi < 8; ++mi) {
        int m = wm * 128 + mi * 16 + quad * 4;
        union { unsigned u[2]; unsigned long long ull; } pkd;
        pkd.u[0] = pk2(acc[mi][ni][0] + bvv, acc[mi][ni][1] + bvv);
        pkd.u[1] = pk2(acc[mi][ni][2] + bvv, acc[mi][ni][3] + bvv);
        *(unsigned long long*)(lds + n * 264 + m) = pkd.ull;
      }
    }
    barrier_raw();
#pragma unroll
    for (int p = 0; p < 16; ++p) {
      int rn = (t >> 5) + p * 16;
      int h = (nq + rn) >> 6, d = rn & 63;
      *(bfrag*)(Vt + ((long)((b << 4) + h) * 64 + d) * 2048 + sbase + seg) =
          *(const bfrag*)(lds + rn * 264 + seg);
    }
  }
}

// ---------------- out-projection: 128x64, BK=32, gload_lds dbuf -----------
__global__ __launch_bounds__(256) void gemm_out(const bf16* __restrict__ O,
                                                const bf16* __restrict__ Bt,
                                                float* __restrict__ Cf) {
  const int K = 1024;
  __shared__ bf16 As[2][128 * 32];
  __shared__ bf16 Bs[2][64 * 32];
  int id = blockIdx.x;
  int xcd = id & 7, sw = id >> 3;
  int m0 = ((xcd << 2) | (sw & 3)) * 128;
  int n0 = (sw >> 2) * 64;
  int t = threadIdx.x;
  int wave = t >> 6, lane = t & 63, quad = lane >> 4, col = lane & 15;
  int wr = (wave >> 1) * 64, wc = (wave & 1) * 32;
  f32x4 acc[2][4] = {};

  int schunk = (lane & 3) ^ ((lane >> 2) & 3);
  int arow = m0 + wave * 32 + (lane >> 2);
  int ob = arow >> 11, os = arow & 2047;
  const bf16* Asrc = O + (long)ob * 2097152 + (long)os * 64 + schunk * 8;
  const bf16* Bsrc = Bt + (long)(n0 + wave * 16 + (lane >> 2)) * K + schunk * 8;
  int la0 = (wave * 32) * 32;
  int lb0 = (wave * 16) * 32;
  int rdoff = ((quad ^ (col & 3)) << 3);

#define OUT_STAGE(bi, k0n)                                            \
  {                                                                   \
    long ka = ((long)((k0n) >> 6)) * 131072 + ((k0n) & 32);           \
    gload16(Asrc + ka, &As[bi][la0]);                                 \
    gload16(Asrc + ka + 16 * 64, &As[bi][la0 + 16 * 32]);             \
    gload16(Bsrc + (k0n), &Bs[bi][lb0]);                              \
  }

  OUT_STAGE(0, 0);
  __syncthreads();
  for (int k0 = 0; k0 < K; k0 += 32) {
    int cur = (k0 >> 5) & 1;
    if (k0 + 32 < K) OUT_STAGE(cur ^ 1, k0 + 32);
    bfrag ra[4], rb[2];
#pragma unroll
    for (int i = 0; i < 4; ++i)
      ra[i] = *(const bfrag*)(&As[cur][(wr + 16 * i + col) * 32 + rdoff]);
#pragma unroll
    for (int c = 0; c < 2; ++c)
      rb[c] = *(const bfrag*)(&Bs[cur][(wc + 16 * c + col) * 32 + rdoff]);
#pragma unroll
    for (int c = 0; c < 2; ++c)
#pragma unroll
      for (int i = 0; i < 4; ++i) acc[c][i] = MFMA16(ra[i], rb[c], acc[c][i]);
    __syncthreads();
  }
#undef OUT_STAGE

#pragma unroll
  for (int c = 0; c < 2; ++c) {
    int n = n0 + wc + 16 * c + col;
#pragma unroll
    for (int i = 0; i < 4; ++i)
#pragma unroll
      for (int r = 0; r < 4; ++r) {
        int m = m0 + wr + 16 * i + quad * 4 + r;
        Cf[(long)m * 1024 + n] = acc[c][i][r];
      }
  }
}

// ---------------- flash attention: S^T dataflow, 2-barrier pipeline -------
// Q/K head-major [b][h][s][d] (Q pre-scaled); Vt [b][h][d][s]; O head-major.
// S^T = MFMA32(A=K_rows, B=Q_rows): C cols = q (lanes), rows = j (regs).
// p = exp2(s) directly (scale folded into Q; constant bias cancels in lsum).
// P^T feeds PV's B operand via v_permlane32_swap_b32.
// O^T = MFMA32(A=V^T from Vs[d][j], B=P^T): cols = q, rows = d.
// Prefetch loads: wave-uniform base (jn) + constant lane offset.
__global__ __launch_bounds__(256) void attn_kernel(const bf16* __restrict__ Q,
                                                   const bf16* __restrict__ K_,
                                                   const bf16* __restrict__ Vt,
                                                   bf16* __restrict__ O) {
  int id = blockIdx.x;             // 1024 blocks
  int xcd = id & 7, jj = id >> 3;
  int qt = 31 - (jj >> 2);         // LPT
  int bh = ((jj & 3) << 3) | xcd;  // 4 bh per XCD

  __shared__ bf16 Ks[128][72];     // [j][d]; f32 Osc[64][68] overlay in epilogue
  __shared__ bf16 Vs[64][136];     // [d][j]; Lsc + Of overlay in epilogue

  int t = threadIdx.x, wave = t >> 6, lane = t & 63;
  int qh = wave >> 1, jh = wave & 1, hi = lane >> 5, l5 = lane & 31;

  int krow = t >> 3, kg = (t & 7) * 8;
  int vrow = t >> 4, vg = (t & 15) * 8;
  // uniform bases + constant lane offsets for prefetch
  const bf16* KuBase = K_ + (long)bh * 2048 * 64;
  const bf16* VuBase = Vt + (long)bh * 64 * 2048;
  int kL = krow * 64 + kg;         // lane-const
  int vL = vrow * 2048 + vg;       // lane-const

  int q0 = qt * 64;
  int nj = (qt >> 1) + 1;
  int qi = q0 + 32 * qh + l5;      // this lane's global q index

  bfrag qa[4];
  const bf16* qp = Q + ((long)bh * 2048 + q0 + 32 * qh + l5) * 64 + hi * 8;
#pragma unroll
  for (int kd = 0; kd < 4; ++kd) qa[kd] = *(const bfrag*)(qp + kd * 16);

  f32x16 o0, o1;                   // O^T partials: rows d / d+32, col q
  float lsum = 0.f;                // per-lane: sum over this wave's j-half
#pragma unroll
  for (int r = 0; r < 16; ++r) { o0[r] = 0.f; o1[r] = 0.f; }

  // prefetch j-tile 0 (both K and V)
  bfrag kreg[4], vreg[4];
#pragma unroll
  for (int i = 0; i < 4; ++i) {
    kreg[i] = *(const bfrag*)(KuBase + kL + i * 2048);
    vreg[i] = *(const bfrag*)(VuBase + vL + i * 32768);
  }

  for (int jt = 0; jt < nj; ++jt) {
    int j0 = jt * 128;
    __syncthreads();               // prev iter's Ks/Vs reads complete
#pragma unroll
    for (int i = 0; i < 4; ++i) {
      *(bfrag*)(&Ks[krow + 32 * i][kg]) = kreg[i];
      *(bfrag*)(&Vs[vrow + 16 * i][vg]) = vreg[i];
    }
    int jn = (jt + 1 < nj) ? j0 + 128 : j0;       // uniform
    const bf16* kp = KuBase + (long)jn * 64;      // uniform base
    const bf16* vp = VuBase + jn;                 // uniform base
#pragma unroll
    for (int i = 0; i < 4; ++i) {
      kreg[i] = *(const bfrag*)(kp + kL + i * 2048);
      vreg[i] = *(const bfrag*)(vp + vL + i * 32768);
    }
    __syncthreads();               // Ks/Vs ready for all waves

    bool lastT = (jt == nj - 1);
    // even qt: last tile's jh==1 half (j in [q0+64,q0+128)) is fully masked.
    if (lastT && jh == 1 && ((qt & 1) == 0)) continue;

    // S^T: per wave 64j (own half) x 32q. A = K rows, B = Q rows.
    f32x16 s0, s1;
#pragma unroll
    for (int r = 0; r < 16; ++r) { s0[r] = 0.f; s1[r] = 0.f; }
    __builtin_amdgcn_s_setprio(1);
#pragma unroll
    for (int kd = 0; kd < 4; ++kd) {
      bfrag ka0 = *(const bfrag*)(&Ks[jh * 64 + l5][kd * 16 + hi * 8]);
      bfrag ka1 = *(const bfrag*)(&Ks[jh * 64 + 32 + l5][kd * 16 + hi * 8]);
      s0 = MFMA32(ka0, qa[kd], s0);
      s1 = MFMA32(ka1, qa[kd], s1);
    }
    __builtin_amdgcn_s_setprio(0);

    // softmax in-register; pack P^T bf16 groups (g[jb][0..3] = r0-3,4-7,8-11,12-15)
    unsigned g[2][4][2];
#pragma unroll
    for (int jb = 0; jb < 2; ++jb) {
      float pv[16];
      float ls = 0.f;
#pragma unroll
      for (int r = 0; r < 16; ++r) {
        int jl = (r & 3) + 8 * (r >> 2) + 4 * hi;        // j within 32-block
        int j = j0 + jh * 64 + jb * 32 + jl;
        float sv = jb ? s1[r] : s0[r];
        float p = __builtin_amdgcn_exp2f(sv);
        if (lastT) p = (j <= qi) ? p : 0.f;
        ls += p;
        pv[r] = p;
      }
      lsum += ls;
#pragma unroll
      for (int gg = 0; gg < 4; ++gg) {
        g[jb][gg][0] = pk2(pv[4 * gg], pv[4 * gg + 1]);
        g[jb][gg][1] = pk2(pv[4 * gg + 2], pv[4 * gg + 3]);
      }
    }

    // PV: O^T += V^T * P^T over own j-half
    __builtin_amdgcn_s_setprio(1);
#pragma unroll
    for (int jb = 0; jb < 2; ++jb) {
#pragma unroll
      for (int c = 0; c < 2; ++c) {
        // B-frag jj0..7 for k-chunk c: groups 2c (r-lo) and 2c+1 (r-hi).
        unsigned a0 = g[jb][2 * c][0], a1 = g[jb][2 * c][1];
        unsigned b0 = g[jb][2 * c + 1][0], b1 = g[jb][2 * c + 1][1];
        asm("v_permlane32_swap_b32 %0, %1" : "+v"(a0), "+v"(b0));
        asm("v_permlane32_swap_b32 %0, %1" : "+v"(a1), "+v"(b1));
        union { unsigned u[4]; bfrag f; } pf;
        pf.u[0] = a0;
        pf.u[1] = a1;
        pf.u[2] = b0;
        pf.u[3] = b1;
        int kk = jh * 64 + jb * 32 + c * 16 + hi * 8;
        bfrag av0 = *(const bfrag*)(&Vs[l5][kk]);
        bfrag av1 = *(const bfrag*)(&Vs[32 + l5][kk]);
        o0 = MFMA32(av0, pf.f, o0);
        o1 = MFMA32(av1, pf.f, o1);
      }
    }
    __builtin_amdgcn_s_setprio(0);
  }

  // combine hi-halves of lsum (same q, different j-sets)
  lsum += __shfl_xor(lsum, 32, 64);

  __syncthreads();   // all Ks/Vs reads done; overlay scratch
  float* Osc = (float*)&Ks[0][0];                    // [64 q][68 d]
  float* Lsc = (float*)&Vs[0][0];                    // [64 q]
  bf16* Of = (bf16*)((char*)&Vs[0][0] + 512);        // [64 q][72 d]
  int q = 32 * qh + l5;
  if (jh == 1) {
#pragma unroll
    for (int r = 0; r < 16; ++r) {
      int d = (r & 3) + 8 * (r >> 2) + 4 * hi;
      Osc[q * 68 + d] = o0[r];
      Osc[q * 68 + 32 + d] = o1[r];
    }
    if (hi == 0) Lsc[q] = lsum;
  }
  __syncthreads();
  if (jh == 0) {
    float inv = 1.f / (lsum + Lsc[q]);
#pragma unroll
    for (int r = 0; r < 16; ++r) {
      int d = (r & 3) + 8 * (r >> 2) + 4 * hi;
      Of[q * 72 + d] = __float2bfloat16((o0[r] + Osc[q * 68 + d]) * inv);
      Of[q * 72 + 32 + d] = __float2bfloat16((o1[r] + Osc[q * 68 + 32 + d]) * inv);
    }
  }
  __syncthreads();
  int row = t >> 2, off = (t & 3) * 16;
  bf16* po = O + ((long)bh * 2048 + q0 + row) * 64 + off;
  *(bfrag*)(po) = *(const bfrag*)(&Of[row * 72 + off]);
  *(bfrag*)(po + 8) = *(const bfrag*)(&Of[row * 72 + off + 8]);
}

extern "C" void kernel_launch(void* const* d_in, const int* in_sizes, int n_in,
                              void* d_out, int out_size, void* d_ws, size_t ws_size,
                              hipStream_t stream) {
  const float* x  = (const float*)d_in[0];
  const float* Wq = (const float*)d_in[1];
  const float* bq = (const float*)d_in[2];
  const float* Wk = (const float*)d_in[3];
  const float* bk = (const float*)d_in[4];
  const float* Wv = (const float*)d_in[5];
  const float* bv = (const float*)d_in[6];
  const float* Wo = (const float*)d_in[7];
  float* out = (float*)d_out;

  bf16* ws = (bf16*)d_ws;
  const long MB1 = 1 << 20;
  bf16* WqkvT = ws + 0 * MB1;    // [3072][1024]
  bf16* WoT   = ws + 3 * MB1;
  bf16* Q     = ws + 4 * MB1;    // [b][h][s][d]
  bf16* K_    = ws + 8 * MB1;    // [b][h][s][d]
  bf16* Vt    = ws + 12 * MB1;   // [b][h][d][s]
  bf16* O     = ws + 16 * MB1;   // [b][h][s][d]
  bf16* xb    = ws + 20 * MB1;

  prep_all<<<3072, 256, 0, stream>>>(x, Wq, Wk, Wv, Wo, xb, WqkvT, WoT);
  gemm_qkv128<<<192, 512, 135168, stream>>>(xb, WqkvT, bq, bk, bv, Q, K_, Vt);
  attn_kernel<<<1024, 256, 0, stream>>>(Q, K_, Vt, O);
  gemm_out<<<512, 256, 0, stream>>>(O, WoT, out);
}

// Round 9
// 188.157 us; speedup vs baseline: 1.0364x; 1.0043x over previous
//
#include <hip/hip_runtime.h>
#include <hip/hip_bf16.h>

// MultiHeadAttention: B=2, S=2048, H=16, D=64, E=1024. f32 I/O, bf16 internal.
// R19 vs R18 (FAILED correctness: 8-wave attn raced post-timing, absmax 1.09;
// race not identified by inspection => full revert per m152 discipline):
//  * attn: reverted to R17-proven 4-wave/64-q version verbatim.
//  * gemm_out: BK 32->64 inside the SAME 2-phase template (issue-stage ->
//    reads -> MFMA -> one __syncthreads drain). Halves barrier-drain count
//    (32->16/block) at identical load counts. LDS 24->48KB (3 blocks/CU,
//    grid needs 2). Swizzle switched to the qkv-proven 8-chunk form:
//    source chunk 8*((t&7)^((t>>3)&7)), read xk = (quad*8)^((col&7)<<3)^(kc*32).
//  * qkv (8-phase + LDS-staged epilogue), prep: unchanged from R17.

typedef __hip_bfloat16 bf16;
typedef __attribute__((ext_vector_type(8))) short bfrag;    // 8 bf16 = 4 VGPRs
typedef __attribute__((ext_vector_type(4))) float f32x4;
typedef __attribute__((ext_vector_type(16))) float f32x16;  // 32x32 C/D
typedef __attribute__((ext_vector_type(4))) short short4v;

#define MFMA16(a, b, c) __builtin_amdgcn_mfma_f32_16x16x32_bf16(a, b, c, 0, 0, 0)
#define MFMA32(a, b, c) __builtin_amdgcn_mfma_f32_32x32x16_bf16(a, b, c, 0, 0, 0)

__device__ __forceinline__ unsigned pk2(float a, float b) {
  union { __hip_bfloat162 h; unsigned u; } w;
  w.h = __float22bfloat162_rn(make_float2(a, b));
  return w.u;
}

// async global->LDS, 16B per lane; LDS dest = wave-uniform base + lane*16.
__device__ __forceinline__ void gload16(const bf16* g, bf16* l) {
  __builtin_amdgcn_global_load_lds(
      (const __attribute__((address_space(1))) void*)(g),
      (__attribute__((address_space(3))) void*)(l), 16, 0, 0);
}

// raw barrier with compiler memory fences (keep LDS ops from crossing)
__device__ __forceinline__ void barrier_raw() {
  asm volatile("" ::: "memory");
  __builtin_amdgcn_s_barrier();
  asm volatile("" ::: "memory");
}

// ---------------- fused cast + weight transposes --------------------------
// blocks 0..2047: x f32->bf16. 2048..2815: Wq/Wk/Wv -> WqkvT. 2816..3071: Wo.
__global__ __launch_bounds__(256) void prep_all(const float* __restrict__ x,
                                                const float* __restrict__ Wq,
                                                const float* __restrict__ Wk,
                                                const float* __restrict__ Wv,
                                                const float* __restrict__ Wo,
                                                bf16* __restrict__ xb,
                                                bf16* __restrict__ WqkvT,
                                                bf16* __restrict__ WoT) {
  __shared__ bf16 tile[64][80];
  int id = blockIdx.x;
  int t = threadIdx.x;
  if (id < 2048) {
    int i = id * 2048 + t * 8;
    float4 a = *(const float4*)(x + i);
    float4 b = *(const float4*)(x + i + 4);
    union { bf16 h[8]; bfrag v; } tmp;
    tmp.h[0] = __float2bfloat16(a.x); tmp.h[1] = __float2bfloat16(a.y);
    tmp.h[2] = __float2bfloat16(a.z); tmp.h[3] = __float2bfloat16(a.w);
    tmp.h[4] = __float2bfloat16(b.x); tmp.h[5] = __float2bfloat16(b.y);
    tmp.h[6] = __float2bfloat16(b.z); tmp.h[7] = __float2bfloat16(b.w);
    *(bfrag*)(xb + i) = tmp.v;
    return;
  }
  int wid = id - 2048;
  const float* src;
  bf16* dst;
  int srcld, dstld, r0, c0;
  if (wid < 768) {
    int w = wid >> 8, h = (wid >> 4) & 15;
    r0 = (wid & 15) * 64; c0 = 0;
    src = ((w == 0) ? Wq : (w == 1) ? Wk : Wv) + (long)h * 1024 * 64;
    dst = WqkvT + ((long)w * 1024 + h * 64) * 1024;
    srcld = 64; dstld = 1024;
  } else {
    int j = wid - 768;
    c0 = (j & 15) * 64; r0 = (j >> 4) * 64;
    src = Wo; dst = WoT;
    srcld = 1024; dstld = 1024;
  }
  int lr = t >> 3, lc = (t & 7) << 3;
#pragma unroll
  for (int p = 0; p < 2; ++p) {
    int r = lr + p * 32;
    const float* s = src + (long)(r0 + r) * srcld + c0 + lc;
    union { bf16 h8[8]; bfrag v; } tmp;
#pragma unroll
    for (int j = 0; j < 8; ++j) tmp.h8[j] = __float2bfloat16(s[j]);
    *(bfrag*)(&tile[r][lc]) = tmp.v;
  }
  __syncthreads();
#pragma unroll
  for (int p = 0; p < 2; ++p) {
    int c = lr + p * 32;
    union { bf16 h8[8]; bfrag v; } tmp;
#pragma unroll
    for (int j = 0; j < 8; ++j) tmp.h8[j] = tile[lc + j][c];
    *(bfrag*)(dst + (long)(c0 + c) * dstld + r0 + lc) = tmp.v;
  }
}

// ---------------- fused QKV GEMM: 256x256, BK=64, 8-phase counted-vmcnt ---
// C[4096][3072] = xb[4096][1024] . WT[3072][1024]^T.
// 512 threads = 8 waves (wm=wave>>2, wn=wave&3); per-wave C = 128x64.
// LDS (dynamic 135168B): k-loop uses first 128KB as A/B double buffers;
// epilogue reuses it as a 256x[264] bf16 output tile.
// Stage unit = 8KB; swizzle: slot s of row r holds chunk s^(r&7).
// vmcnt(2) only at phases 4 and 8 (counted, never 0 in-loop).
__global__ __launch_bounds__(512, 2) void gemm_qkv128(const bf16* __restrict__ xb,
                                                      const bf16* __restrict__ WT,
                                                      const float* __restrict__ bq,
                                                      const float* __restrict__ bk,
                                                      const float* __restrict__ bv,
                                                      bf16* __restrict__ Q,
                                                      bf16* __restrict__ K_,
                                                      bf16* __restrict__ Vt) {
  extern __shared__ bf16 lds[];
  int id = blockIdx.x;
  int xcd = id & 7, idx = id >> 3;
  int tile = xcd * 24 + idx;          // 192 = 16 mt x 12 nt, bijective
  int mt = tile & 15, nt = tile >> 4;
  int m0 = mt * 256, n0 = nt * 256;

  int t = threadIdx.x;
  int wave = t >> 6, lane = t & 63, quad = lane >> 4, col = lane & 15;
  int wm = wave >> 2, wn = wave & 3;

  // staging addresses
  int schunk = 8 * ((t & 7) ^ ((t >> 3) & 7));   // pre-swizzled source chunk
  const bf16* aSrc = xb + (long)(m0 + (t >> 3)) * 1024 + schunk;
  const bf16* bSrc = WT + (long)(n0 + (t >> 3)) * 1024 + schunk;
  int wv512 = wave * 512;                         // wave-uniform LDS sub-base

  // read addresses (element offsets); xoff kc=1 = xoff0 ^ 32
  int xoff0 = (quad * 8) ^ ((col & 7) << 3);
  const bf16* aRdB = lds + wm * 8192 + col * 64;
  const bf16* bRdB = lds + 32768 + (wn >> 1) * 8192 + (wn & 1) * 4096 + col * 64;

  f32x4 acc[8][4] = {};

#define STA(BUF, HALF, G, KS)                                                  \
  gload16(aSrc + (long)((HALF)*128 + (G)*64) * 1024 + (KS)*64,                 \
          lds + (BUF)*16384 + (HALF)*8192 + (G)*4096 + wv512)
#define STB(BUF, HALF, G, KS)                                                  \
  gload16(bSrc + (long)((HALF)*128 + (G)*64) * 1024 + (KS)*64,                 \
          lds + 32768 + (BUF)*16384 + (HALF)*8192 + (G)*4096 + wv512)

#define PHASE(BUF, MH, KC, STAGES, VMW)                                        \
  {                                                                            \
    int xk = xoff0 ^ ((KC)*32);                                                \
    bfrag ra[4], rb[4];                                                        \
    _Pragma("unroll") for (int u = 0; u < 4; ++u) {                            \
      ra[u] = *(const bfrag*)(aRdB + (BUF)*16384 + (MH)*4096 + u * 1024 + xk); \
      rb[u] = *(const bfrag*)(bRdB + (BUF)*16384 + u * 1024 + xk);             \
    }                                                                          \
    STAGES;                                                                    \
    VMW;                                                                       \
    barrier_raw();                                                             \
    __builtin_amdgcn_s_setprio(1);                                             \
    _Pragma("unroll") for (int ni = 0; ni < 4; ++ni)                           \
      _Pragma("unroll") for (int mi2 = 0; mi2 < 4; ++mi2)                      \
        acc[(MH)*4 + mi2][ni] = MFMA16(ra[mi2], rb[ni], acc[(MH)*4 + mi2][ni]);\
    __builtin_amdgcn_s_setprio(0);                                             \
    barrier_raw();                                                             \
  }

#define VM2 asm volatile("s_waitcnt vmcnt(2)" ::: "memory")
#define NOVM

  // prologue: buf0 <- ks0 (8 units), buf1 A-g0 <- ks1 (mimics steady p8)
  STA(0, 0, 0, 0); STA(0, 1, 0, 0); STA(0, 0, 1, 0); STA(0, 1, 1, 0);
  STB(0, 0, 0, 0); STB(0, 0, 1, 0); STB(0, 1, 0, 0); STB(0, 1, 1, 0);
  STA(1, 0, 0, 1); STA(1, 1, 0, 1);
  VM2;
  barrier_raw();

  for (int it = 0; it < 8; ++it) {
    int ksB = 2 * it + 1;                         // buf1 content, used p5-8
    int kA  = (it < 7) ? 2 * it + 2 : 14;         // buf0 next content (clamped)
    int ksB2 = (it < 7) ? 2 * it + 3 : 15;        // buf1 next content (clamped)
    PHASE(0, 0, 0, { STA(1, 0, 1, ksB); STA(1, 1, 1, ksB); }, NOVM);   // p1
    PHASE(0, 0, 1, { STB(1, 0, 0, ksB); STB(1, 0, 1, ksB); }, NOVM);   // p2
    PHASE(0, 1, 0, { STB(1, 1, 0, ksB); STB(1, 1, 1, ksB); }, NOVM);   // p3
    PHASE(0, 1, 1, { STA(0, 0, 0, kA); STA(0, 1, 0, kA); }, VM2);      // p4
    PHASE(1, 0, 0, { STA(0, 0, 1, kA); STA(0, 1, 1, kA); }, NOVM);     // p5
    PHASE(1, 0, 1, { STB(0, 0, 0, kA); STB(0, 0, 1, kA); }, NOVM);     // p6
    PHASE(1, 1, 0, { STB(0, 1, 0, kA); STB(0, 1, 1, kA); }, NOVM);     // p7
    PHASE(1, 1, 1, { STA(1, 0, 0, ksB2); STA(1, 1, 0, ksB2); }, VM2);  // p8
  }
#undef PHASE
#undef STA
#undef STB
#undef VM2
#undef NOVM

  // ---- epilogue: drain stray prefetches, repurpose LDS as output tile ----
  asm volatile("s_waitcnt vmcnt(0)" ::: "memory");
  barrier_raw();

  int sel = n0 >> 10;   // 0=Q, 1=K, 2=V (256-tiles never cross 1024 boundary)
  const float* bias = (sel == 0) ? bq : (sel == 1) ? bk : bv;
  float qs = (sel == 0) ? 0.18033688f : 1.0f;   // (1/8)*log2(e) folded into Q
  int b = m0 >> 11, sbase = m0 & 2047, nq = n0 & 1023;
  int seg = (t & 31) * 8;

  if (sel < 2) {
    // stage [m][264 n]
#pragma unroll
    for (int ni = 0; ni < 4; ++ni) {
      int n = wn * 64 + ni * 16 + col;
      float bvv = bias[nq + n];
#pragma unroll
      for (int mi = 0; mi < 8; ++mi) {
        int mrow = wm * 128 + mi * 16 + quad * 4;
#pragma unroll
        for (int r = 0; r < 4; ++r)
          lds[(mrow + r) * 264 + n] = __float2bfloat16((acc[mi][ni][r] + bvv) * qs);
      }
    }
    barrier_raw();
    bf16* dst = (sel == 0) ? Q : K_;
    int h = (nq + seg) >> 6, d = seg & 63;
    long gb = ((long)((b << 4) + h) * 2048 + sbase) * 64 + d;
#pragma unroll
    for (int p = 0; p < 16; ++p) {
      int row = (t >> 5) + p * 16;
      *(bfrag*)(dst + gb + (long)row * 64) = *(const bfrag*)(lds + row * 264 + seg);
    }
  } else {
    // stage transposed [n][264 m] with packed b64 writes
#pragma unroll
    for (int ni = 0; ni < 4; ++ni) {
      int n = wn * 64 + ni * 16 + col;
      float bvv = bias[nq + n];
#pragma unroll
      for (int mi = 0; mi < 8; ++mi) {
        int m = wm * 128 + mi * 16 + quad * 4;
        union { unsigned u[2]; unsigned long long ull; } pkd;
        pkd.u[0] = pk2(acc[mi][ni][0] + bvv, acc[mi][ni][1] + bvv);
        pkd.u[1] = pk2(acc[mi][ni][2] + bvv, acc[mi][ni][3] + bvv);
        *(unsigned long long*)(lds + n * 264 + m) = pkd.ull;
      }
    }
    barrier_raw();
#pragma unroll
    for (int p = 0; p < 16; ++p) {
      int rn = (t >> 5) + p * 16;
      int h = (nq + rn) >> 6, d = rn & 63;
      *(bfrag*)(Vt + ((long)((b << 4) + h) * 64 + d) * 2048 + sbase + seg) =
          *(const bfrag*)(lds + rn * 264 + seg);
    }
  }
}

// ---------------- out-projection: 128x64, BK=64, gload_lds dbuf -----------
// Same 2-phase template as before, BK doubled: 16 barrier-drains (was 32).
// LDS tile [rows][64] linear, swizzled: slot s of row r holds chunk s^(r&7).
__global__ __launch_bounds__(256) void gemm_out(const bf16* __restrict__ O,
                                                const bf16* __restrict__ Bt,
                                                float* __restrict__ Cf) {
  const int K = 1024;
  __shared__ bf16 As[2][128 * 64];
  __shared__ bf16 Bs[2][64 * 64];
  int id = blockIdx.x;
  int xcd = id & 7, sw = id >> 3;
  int m0 = ((xcd << 2) | (sw & 3)) * 128;
  int n0 = (sw >> 2) * 64;
  int t = threadIdx.x;
  int wave = t >> 6, lane = t & 63, quad = lane >> 4, col = lane & 15;
  int wr = (wave >> 1) * 64, wc = (wave & 1) * 32;
  f32x4 acc[2][4] = {};

  // staging: per gload16, 256 thr cover 32 rows x 64 k. Source row for
  // instr i = m0|n0 + (t>>3) + 32*i; pre-swizzled chunk 8*((t&7)^((t>>3)&7)).
  int schunk = 8 * ((t & 7) ^ ((t >> 3) & 7));
  int ob = m0 >> 11;                       // 128-row tile never crosses b
  const bf16* AsrcB = O + (long)ob * 2097152 + (long)((m0 & 2047) + (t >> 3)) * 64 + schunk;
  const bf16* BsrcB = Bt + (long)(n0 + (t >> 3)) * K + schunk;
  int wv = wave * 512;                     // wave-uniform LDS sub-base
  int xoff0 = (quad * 8) ^ ((col & 7) << 3);

#define OUT_STAGE(bi, k0n)                                                 \
  {                                                                        \
    long ko = ((long)((k0n) >> 6)) * 131072;                               \
    _Pragma("unroll") for (int i = 0; i < 4; ++i)                          \
      gload16(AsrcB + ko + (long)(32 * i) * 64, &As[bi][i * 2048 + wv]);   \
    _Pragma("unroll") for (int i = 0; i < 2; ++i)                          \
      gload16(BsrcB + (k0n) + (long)(32 * i) * K, &Bs[bi][i * 2048 + wv]); \
  }

  OUT_STAGE(0, 0);
  __syncthreads();
  for (int k0 = 0; k0 < K; k0 += 64) {
    int cur = (k0 >> 6) & 1;
    if (k0 + 64 < K) OUT_STAGE(cur ^ 1, k0 + 64);
#pragma unroll
    for (int kc = 0; kc < 2; ++kc) {
      int xk = xoff0 ^ (kc * 32);
      bfrag ra[4], rb[2];
#pragma unroll
      for (int i = 0; i < 4; ++i)
        ra[i] = *(const bfrag*)(&As[cur][(wr + 16 * i + col) * 64 + xk]);
#pragma unroll
      for (int c = 0; c < 2; ++c)
        rb[c] = *(const bfrag*)(&Bs[cur][(wc + 16 * c + col) * 64 + xk]);
#pragma unroll
      for (int c = 0; c < 2; ++c)
#pragma unroll
        for (int i = 0; i < 4; ++i) acc[c][i] = MFMA16(ra[i], rb[c], acc[c][i]);
    }
    __syncthreads();
  }
#undef OUT_STAGE

#pragma unroll
  for (int c = 0; c < 2; ++c) {
    int n = n0 + wc + 16 * c + col;
#pragma unroll
    for (int i = 0; i < 4; ++i)
#pragma unroll
      for (int r = 0; r < 4; ++r) {
        int m = m0 + wr + 16 * i + quad * 4 + r;
        Cf[(long)m * 1024 + n] = acc[c][i][r];
      }
  }
}

// ---------------- flash attention: S^T dataflow, 2-barrier pipeline -------
// (R17-proven version, reverted verbatim after R18's 8-wave race.)
// Q/K head-major [b][h][s][d] (Q pre-scaled); Vt [b][h][d][s]; O head-major.
// S^T = MFMA32(A=K_rows, B=Q_rows): C cols = q (lanes), rows = j (regs).
// p = exp2(s) directly (scale folded into Q; constant bias cancels in lsum).
// P^T feeds PV's B operand via v_permlane32_swap_b32.
// O^T = MFMA32(A=V^T from Vs[d][j], B=P^T): cols = q, rows = d.
// Prefetch loads: wave-uniform base (jn) + constant lane offset.
__global__ __launch_bounds__(256) void attn_kernel(const bf16* __restrict__ Q,
                                                   const bf16* __restrict__ K_,
                                                   const bf16* __restrict__ Vt,
                                                   bf16* __restrict__ O) {
  int id = blockIdx.x;             // 1024 blocks
  int xcd = id & 7, jj = id >> 3;
  int qt = 31 - (jj >> 2);         // LPT
  int bh = ((jj & 3) << 3) | xcd;  // 4 bh per XCD

  __shared__ bf16 Ks[128][72];     // [j][d]; f32 Osc[64][68] overlay in epilogue
  __shared__ bf16 Vs[64][136];     // [d][j]; Lsc + Of overlay in epilogue

  int t = threadIdx.x, wave = t >> 6, lane = t & 63;
  int qh = wave >> 1, jh = wave & 1, hi = lane >> 5, l5 = lane & 31;

  int krow = t >> 3, kg = (t & 7) * 8;
  int vrow = t >> 4, vg = (t & 15) * 8;
  // uniform bases + constant lane offsets for prefetch
  const bf16* KuBase = K_ + (long)bh * 2048 * 64;
  const bf16* VuBase = Vt + (long)bh * 64 * 2048;
  int kL = krow * 64 + kg;         // lane-const
  int vL = vrow * 2048 + vg;       // lane-const

  int q0 = qt * 64;
  int nj = (qt >> 1) + 1;
  int qi = q0 + 32 * qh + l5;      // this lane's global q index

  bfrag qa[4];
  const bf16* qp = Q + ((long)bh * 2048 + q0 + 32 * qh + l5) * 64 + hi * 8;
#pragma unroll
  for (int kd = 0; kd < 4; ++kd) qa[kd] = *(const bfrag*)(qp + kd * 16);

  f32x16 o0, o1;                   // O^T partials: rows d / d+32, col q
  float lsum = 0.f;                // per-lane: sum over this wave's j-half
#pragma unroll
  for (int r = 0; r < 16; ++r) { o0[r] = 0.f; o1[r] = 0.f; }

  // prefetch j-tile 0 (both K and V)
  bfrag kreg[4], vreg[4];
#pragma unroll
  for (int i = 0; i < 4; ++i) {
    kreg[i] = *(const bfrag*)(KuBase + kL + i * 2048);
    vreg[i] = *(const bfrag*)(VuBase + vL + i * 32768);
  }

  for (int jt = 0; jt < nj; ++jt) {
    int j0 = jt * 128;
    __syncthreads();               // prev iter's Ks/Vs reads complete
#pragma unroll
    for (int i = 0; i < 4; ++i) {
      *(bfrag*)(&Ks[krow + 32 * i][kg]) = kreg[i];
      *(bfrag*)(&Vs[vrow + 16 * i][vg]) = vreg[i];
    }
    int jn = (jt + 1 < nj) ? j0 + 128 : j0;       // uniform
    const bf16* kp = KuBase + (long)jn * 64;      // uniform base
    const bf16* vp = VuBase + jn;                 // uniform base
#pragma unroll
    for (int i = 0; i < 4; ++i) {
      kreg[i] = *(const bfrag*)(kp + kL + i * 2048);
      vreg[i] = *(const bfrag*)(vp + vL + i * 32768);
    }
    __syncthreads();               // Ks/Vs ready for all waves

    bool lastT = (jt == nj - 1);
    // even qt: last tile's jh==1 half (j in [q0+64,q0+128)) is fully masked.
    if (lastT && jh == 1 && ((qt & 1) == 0)) continue;

    // S^T: per wave 64j (own half) x 32q. A = K rows, B = Q rows.
    f32x16 s0, s1;
#pragma unroll
    for (int r = 0; r < 16; ++r) { s0[r] = 0.f; s1[r] = 0.f; }
    __builtin_amdgcn_s_setprio(1);
#pragma unroll
    for (int kd = 0; kd < 4; ++kd) {
      bfrag ka0 = *(const bfrag*)(&Ks[jh * 64 + l5][kd * 16 + hi * 8]);
      bfrag ka1 = *(const bfrag*)(&Ks[jh * 64 + 32 + l5][kd * 16 + hi * 8]);
      s0 = MFMA32(ka0, qa[kd], s0);
      s1 = MFMA32(ka1, qa[kd], s1);
    }
    __builtin_amdgcn_s_setprio(0);

    // softmax in-register; pack P^T bf16 groups (g[jb][0..3] = r0-3,4-7,8-11,12-15)
    unsigned g[2][4][2];
#pragma unroll
    for (int jb = 0; jb < 2; ++jb) {
      float pv[16];
      float ls = 0.f;
#pragma unroll
      for (int r = 0; r < 16; ++r) {
        int jl = (r & 3) + 8 * (r >> 2) + 4 * hi;        // j within 32-block
        int j = j0 + jh * 64 + jb * 32 + jl;
        float sv = jb ? s1[r] : s0[r];
        float p = __builtin_amdgcn_exp2f(sv);
        if (lastT) p = (j <= qi) ? p : 0.f;
        ls += p;
        pv[r] = p;
      }
      lsum += ls;
#pragma unroll
      for (int gg = 0; gg < 4; ++gg) {
        g[jb][gg][0] = pk2(pv[4 * gg], pv[4 * gg + 1]);
        g[jb][gg][1] = pk2(pv[4 * gg + 2], pv[4 * gg + 3]);
      }
    }

    // PV: O^T += V^T * P^T over own j-half
    __builtin_amdgcn_s_setprio(1);
#pragma unroll
    for (int jb = 0; jb < 2; ++jb) {
#pragma unroll
      for (int c = 0; c < 2; ++c) {
        // B-frag jj0..7 for k-chunk c: groups 2c (r-lo) and 2c+1 (r-hi).
        unsigned a0 = g[jb][2 * c][0], a1 = g[jb][2 * c][1];
        unsigned b0 = g[jb][2 * c + 1][0], b1 = g[jb][2 * c + 1][1];
        asm("v_permlane32_swap_b32 %0, %1" : "+v"(a0), "+v"(b0));
        asm("v_permlane32_swap_b32 %0, %1" : "+v"(a1), "+v"(b1));
        union { unsigned u[4]; bfrag f; } pf;
        pf.u[0] = a0;
        pf.u[1] = a1;
        pf.u[2] = b0;
        pf.u[3] = b1;
        int kk = jh * 64 + jb * 32 + c * 16 + hi * 8;
        bfrag av0 = *(const bfrag*)(&Vs[l5][kk]);
        bfrag av1 = *(const bfrag*)(&Vs[32 + l5][kk]);
        o0 = MFMA32(av0, pf.f, o0);
        o1 = MFMA32(av1, pf.f, o1);
      }
    }
    __builtin_amdgcn_s_setprio(0);
  }

  // combine hi-halves of lsum (same q, different j-sets)
  lsum += __shfl_xor(lsum, 32, 64);

  __syncthreads();   // all Ks/Vs reads done; overlay scratch
  float* Osc = (float*)&Ks[0][0];                    // [64 q][68 d]
  float* Lsc = (float*)&Vs[0][0];                    // [64 q]
  bf16* Of = (bf16*)((char*)&Vs[0][0] + 512);        // [64 q][72 d]
  int q = 32 * qh + l5;
  if (jh == 1) {
#pragma unroll
    for (int r = 0; r < 16; ++r) {
      int d = (r & 3) + 8 * (r >> 2) + 4 * hi;
      Osc[q * 68 + d] = o0[r];
      Osc[q * 68 + 32 + d] = o1[r];
    }
    if (hi == 0) Lsc[q] = lsum;
  }
  __syncthreads();
  if (jh == 0) {
    float inv = 1.f / (lsum + Lsc[q]);
#pragma unroll
    for (int r = 0; r < 16; ++r) {
      int d = (r & 3) + 8 * (r >> 2) + 4 * hi;
      Of[q * 72 + d] = __float2bfloat16((o0[r] + Osc[q * 68 + d]) * inv);
      Of[q * 72 + 32 + d] = __float2bfloat16((o1[r] + Osc[q * 68 + 32 + d]) * inv);
    }
  }
  __syncthreads();
  int row = t >> 2, off = (t & 3) * 16;
  bf16* po = O + ((long)bh * 2048 + q0 + row) * 64 + off;
  *(bfrag*)(po) = *(const bfrag*)(&Of[row * 72 + off]);
  *(bfrag*)(po + 8) = *(const bfrag*)(&Of[row * 72 + off + 8]);
}

extern "C" void kernel_launch(void* const* d_in, const int* in_sizes, int n_in,
                              void* d_out, int out_size, void* d_ws, size_t ws_size,
                              hipStream_t stream) {
  const float* x  = (const float*)d_in[0];
  const float* Wq = (const float*)d_in[1];
  const float* bq = (const float*)d_in[2];
  const float* Wk = (const float*)d_in[3];
  const float* bk = (const float*)d_in[4];
  const float* Wv = (const float*)d_in[5];
  const float* bv = (const float*)d_in[6];
  const float* Wo = (const float*)d_in[7];
  float* out = (float*)d_out;

  bf16* ws = (bf16*)d_ws;
  const long MB1 = 1 << 20;
  bf16* WqkvT = ws + 0 * MB1;    // [3072][1024]
  bf16* WoT   = ws + 3 * MB1;
  bf16* Q     = ws + 4 * MB1;    // [b][h][s][d]
  bf16* K_    = ws + 8 * MB1;    // [b][h][s][d]
  bf16* Vt    = ws + 12 * MB1;   // [b][h][d][s]
  bf16* O     = ws + 16 * MB1;   // [b][h][s][d]
  bf16* xb    = ws + 20 * MB1;

  prep_all<<<3072, 256, 0, stream>>>(x, Wq, Wk, Wv, Wo, xb, WqkvT, WoT);
  gemm_qkv128<<<192, 512, 135168, stream>>>(xb, WqkvT, bq, bk, bv, Q, K_, Vt);
  attn_kernel<<<1024, 256, 0, stream>>>(Q, K_, Vt, O);
  gemm_out<<<512, 256, 0, stream>>>(O, WoT, out);
}

// Round 10
// 186.351 us; speedup vs baseline: 1.0465x; 1.0097x over previous
//
#include <hip/hip_runtime.h>
#include <hip/hip_bf16.h>

// MultiHeadAttention: B=2, S=2048, H=16, D=64, E=1024. f32 I/O, bf16 internal.
// R20 vs R19 (188.2us; attn ~42 top, qkv below cutoff but grid=192 blocks on
// 256 CUs = hard 25% CU-coverage loss):
//  * gemm_qkv: 256x192 tiles -> 16x16 = 256 blocks = exactly 1/CU. Same
//    8-phase counted-vmcnt K-loop (B now 3 stage-units/K-step, 7 units per
//    half-iter; outstanding at each VM wait = 9 -> vmcnt(2) unchanged).
//    Epilogue variant-dispatched per n0 (192-tiles cross Q/K/V boundaries):
//    pure-QK (per-col sel/bias/qs, [m][200]), mixed K|V at n0=1920 ([m][136]
//    + transposed [n][264] V region), pure-V ([n][264]). All branches
//    wave-uniform (boundaries on 16-col multiples). LDS 114688B, 1 block/CU.
//  * attn (R17-proven), gemm_out (BK=64), prep: unchanged.

typedef __hip_bfloat16 bf16;
typedef __attribute__((ext_vector_type(8))) short bfrag;    // 8 bf16 = 4 VGPRs
typedef __attribute__((ext_vector_type(4))) float f32x4;
typedef __attribute__((ext_vector_type(16))) float f32x16;  // 32x32 C/D
typedef __attribute__((ext_vector_type(4))) short short4v;

#define MFMA16(a, b, c) __builtin_amdgcn_mfma_f32_16x16x32_bf16(a, b, c, 0, 0, 0)
#define MFMA32(a, b, c) __builtin_amdgcn_mfma_f32_32x32x16_bf16(a, b, c, 0, 0, 0)

__device__ __forceinline__ unsigned pk2(float a, float b) {
  union { __hip_bfloat162 h; unsigned u; } w;
  w.h = __float22bfloat162_rn(make_float2(a, b));
  return w.u;
}

// async global->LDS, 16B per lane; LDS dest = wave-uniform base + lane*16.
__device__ __forceinline__ void gload16(const bf16* g, bf16* l) {
  __builtin_amdgcn_global_load_lds(
      (const __attribute__((address_space(1))) void*)(g),
      (__attribute__((address_space(3))) void*)(l), 16, 0, 0);
}

// raw barrier with compiler memory fences (keep LDS ops from crossing)
__device__ __forceinline__ void barrier_raw() {
  asm volatile("" ::: "memory");
  __builtin_amdgcn_s_barrier();
  asm volatile("" ::: "memory");
}

// ---------------- fused cast + weight transposes --------------------------
// blocks 0..2047: x f32->bf16. 2048..2815: Wq/Wk/Wv -> WqkvT. 2816..3071: Wo.
__global__ __launch_bounds__(256) void prep_all(const float* __restrict__ x,
                                                const float* __restrict__ Wq,
                                                const float* __restrict__ Wk,
                                                const float* __restrict__ Wv,
                                                const float* __restrict__ Wo,
                                                bf16* __restrict__ xb,
                                                bf16* __restrict__ WqkvT,
                                                bf16* __restrict__ WoT) {
  __shared__ bf16 tile[64][80];
  int id = blockIdx.x;
  int t = threadIdx.x;
  if (id < 2048) {
    int i = id * 2048 + t * 8;
    float4 a = *(const float4*)(x + i);
    float4 b = *(const float4*)(x + i + 4);
    union { bf16 h[8]; bfrag v; } tmp;
    tmp.h[0] = __float2bfloat16(a.x); tmp.h[1] = __float2bfloat16(a.y);
    tmp.h[2] = __float2bfloat16(a.z); tmp.h[3] = __float2bfloat16(a.w);
    tmp.h[4] = __float2bfloat16(b.x); tmp.h[5] = __float2bfloat16(b.y);
    tmp.h[6] = __float2bfloat16(b.z); tmp.h[7] = __float2bfloat16(b.w);
    *(bfrag*)(xb + i) = tmp.v;
    return;
  }
  int wid = id - 2048;
  const float* src;
  bf16* dst;
  int srcld, dstld, r0, c0;
  if (wid < 768) {
    int w = wid >> 8, h = (wid >> 4) & 15;
    r0 = (wid & 15) * 64; c0 = 0;
    src = ((w == 0) ? Wq : (w == 1) ? Wk : Wv) + (long)h * 1024 * 64;
    dst = WqkvT + ((long)w * 1024 + h * 64) * 1024;
    srcld = 64; dstld = 1024;
  } else {
    int j = wid - 768;
    c0 = (j & 15) * 64; r0 = (j >> 4) * 64;
    src = Wo; dst = WoT;
    srcld = 1024; dstld = 1024;
  }
  int lr = t >> 3, lc = (t & 7) << 3;
#pragma unroll
  for (int p = 0; p < 2; ++p) {
    int r = lr + p * 32;
    const float* s = src + (long)(r0 + r) * srcld + c0 + lc;
    union { bf16 h8[8]; bfrag v; } tmp;
#pragma unroll
    for (int j = 0; j < 8; ++j) tmp.h8[j] = __float2bfloat16(s[j]);
    *(bfrag*)(&tile[r][lc]) = tmp.v;
  }
  __syncthreads();
#pragma unroll
  for (int p = 0; p < 2; ++p) {
    int c = lr + p * 32;
    union { bf16 h8[8]; bfrag v; } tmp;
#pragma unroll
    for (int j = 0; j < 8; ++j) tmp.h8[j] = tile[lc + j][c];
    *(bfrag*)(dst + (long)(c0 + c) * dstld + r0 + lc) = tmp.v;
  }
}

// ---------------- fused QKV GEMM: 256x192, BK=64, 8-phase counted-vmcnt ---
// C[4096][3072] = xb[4096][1024] . WT[3072][1024]^T. 16x16 = 256 blocks.
// 512 threads = 8 waves (wm=wave>>2, wn=wave&3); per-wave C = 128x48.
// LDS (dynamic 114688B = 57344 el):
//   A: [buf][half][128][64] at buf*16384 + half*8192   (32768 el)
//   B: [buf][192][64]       at 32768 + buf*12288       (24576 el)
// Stage unit = 8KB = 64 rows x 64 k (1 gload16/thread). Units per K-step:
// A 4 (U0=h0g0,U1=h1g0,U2=h0g1,U3=h1g1) + B 3 (U4..U6) = 7.
// Swizzle: slot s of row r holds chunk s^(r&7). vmcnt(2) at p4/p8 only.
__global__ __launch_bounds__(512, 2) void gemm_qkv128(const bf16* __restrict__ xb,
                                                      const bf16* __restrict__ WT,
                                                      const float* __restrict__ bq,
                                                      const float* __restrict__ bk,
                                                      const float* __restrict__ bv,
                                                      bf16* __restrict__ Q,
                                                      bf16* __restrict__ K_,
                                                      bf16* __restrict__ Vt) {
  extern __shared__ bf16 lds[];
  int id = blockIdx.x;
  int xcd = id & 7, idx = id >> 3;
  int tile = xcd * 32 + idx;          // 256 = 16 mt x 16 nt, bijective
  int mt = tile & 15, nt = tile >> 4;
  int m0 = mt * 256, n0 = nt * 192;

  int t = threadIdx.x;
  int wave = t >> 6, lane = t & 63, quad = lane >> 4, col = lane & 15;
  int wm = wave >> 2, wn = wave & 3;

  // staging addresses
  int schunk = 8 * ((t & 7) ^ ((t >> 3) & 7));   // pre-swizzled source chunk
  const bf16* aSrc = xb + (long)(m0 + (t >> 3)) * 1024 + schunk;
  const bf16* bSrc = WT + (long)(n0 + (t >> 3)) * 1024 + schunk;
  int wv512 = wave * 512;                         // wave-uniform LDS sub-base

  // read addresses (element offsets); xk for kc: xoff0 ^ (kc*32)
  int xoff0 = (quad * 8) ^ ((col & 7) << 3);
  const bf16* aRdB = lds + wm * 8192 + col * 64;
  const bf16* bRdB = lds + 32768 + (wn * 48 + col) * 64;

  f32x4 acc[8][3] = {};

#define STA(BUF, HALF, G, KS)                                                  \
  gload16(aSrc + (long)((HALF)*128 + (G)*64) * 1024 + (KS)*64,                 \
          lds + (BUF)*16384 + (HALF)*8192 + (G)*4096 + wv512)
#define STB(BUF, G, KS)                                                        \
  gload16(bSrc + (long)((G)*64) * 1024 + (KS)*64,                              \
          lds + 32768 + (BUF)*12288 + (G)*4096 + wv512)

#define PHASE(BUF, MH, KC, STAGES, VMW)                                        \
  {                                                                            \
    int xk = xoff0 ^ ((KC)*32);                                                \
    bfrag ra[4], rb[3];                                                        \
    _Pragma("unroll") for (int u = 0; u < 4; ++u)                              \
      ra[u] = *(const bfrag*)(aRdB + (BUF)*16384 + (MH)*4096 + u * 1024 + xk); \
    _Pragma("unroll") for (int c2 = 0; c2 < 3; ++c2)                           \
      rb[c2] = *(const bfrag*)(bRdB + (BUF)*12288 + c2 * 1024 + xk);           \
    STAGES;                                                                    \
    VMW;                                                                       \
    barrier_raw();                                                             \
    __builtin_amdgcn_s_setprio(1);                                             \
    _Pragma("unroll") for (int ni = 0; ni < 3; ++ni)                           \
      _Pragma("unroll") for (int mi2 = 0; mi2 < 4; ++mi2)                      \
        acc[(MH)*4 + mi2][ni] = MFMA16(ra[mi2], rb[ni], acc[(MH)*4 + mi2][ni]);\
    __builtin_amdgcn_s_setprio(0);                                             \
    barrier_raw();                                                             \
  }

#define VM2 asm volatile("s_waitcnt vmcnt(2)" ::: "memory")
#define NOVM

  // prologue: buf0 all 7 units (ks0), buf1 U0,U1 (ks1)
  STA(0, 0, 0, 0); STA(0, 1, 0, 0); STA(0, 0, 1, 0); STA(0, 1, 1, 0);
  STB(0, 0, 0); STB(0, 1, 0); STB(0, 2, 0);
  STA(1, 0, 0, 1); STA(1, 1, 0, 1);
  VM2;
  barrier_raw();

  for (int it = 0; it < 8; ++it) {
    int ksB = 2 * it + 1;                         // buf1 content, used p5-8
    int kA  = (it < 7) ? 2 * it + 2 : 14;         // buf0 next content (clamped)
    int ksB2 = (it < 7) ? 2 * it + 3 : 15;        // buf1 next content (clamped)
    PHASE(0, 0, 0, { STA(1, 0, 1, ksB); STA(1, 1, 1, ksB); }, NOVM);   // p1
    PHASE(0, 0, 1, { STB(1, 0, ksB); STB(1, 1, ksB); }, NOVM);         // p2
    PHASE(0, 1, 0, { STB(1, 2, ksB); }, NOVM);                         // p3
    PHASE(0, 1, 1, { STA(0, 0, 0, kA); STA(0, 1, 0, kA); }, VM2);      // p4
    PHASE(1, 0, 0, { STA(0, 0, 1, kA); STA(0, 1, 1, kA); }, NOVM);     // p5
    PHASE(1, 0, 1, { STB(0, 0, kA); STB(0, 1, kA); }, NOVM);           // p6
    PHASE(1, 1, 0, { STB(0, 2, kA); }, NOVM);                          // p7
    PHASE(1, 1, 1, { STA(1, 0, 0, ksB2); STA(1, 1, 0, ksB2); }, VM2);  // p8
  }
#undef PHASE
#undef STA
#undef STB
#undef VM2
#undef NOVM

  // ---- epilogue: drain stray prefetches, repurpose LDS as output tile ----
  asm volatile("s_waitcnt vmcnt(0)" ::: "memory");
  barrier_raw();

  const float SC2 = 0.18033688f;    // (1/8)*log2(e) folded into Q
  int b = m0 >> 11, sbase = m0 & 2047;

  if (n0 < 1920) {
    // ---- pure Q/K-layout tile (may straddle Q|K at 1024; per-col sel) ----
#pragma unroll
    for (int ni = 0; ni < 3; ++ni) {
      int n = wn * 48 + ni * 16 + col;
      int ng = n0 + n;                // < 2048 guaranteed
      int s01 = ng >> 10;             // 0 = Q, 1 = K (uniform per wn,ni)
      float bvv = s01 ? bk[ng & 1023] : bq[ng & 1023];
      float qsv = s01 ? 1.0f : SC2;
#pragma unroll
      for (int mi = 0; mi < 8; ++mi) {
        int mrow = wm * 128 + mi * 16 + quad * 4;
#pragma unroll
        for (int r = 0; r < 4; ++r)
          lds[(mrow + r) * 200 + n] = __float2bfloat16((acc[mi][ni][r] + bvv) * qsv);
      }
    }
    barrier_raw();
    int row = t >> 1, half = t & 1;
#pragma unroll
    for (int s = 0; s < 12; ++s) {
      int cl = 96 * half + 8 * s;
      int ng = n0 + cl;
      int s01 = ng >> 10, within = ng & 1023;
      int h = within >> 6, d = within & 63;
      bf16* dst = s01 ? K_ : Q;
      *(bfrag*)(dst + ((long)((b << 4) + h) * 2048 + sbase + row) * 64 + d) =
          *(const bfrag*)(lds + row * 200 + cl);
    }
  } else if (n0 == 1920) {
    // ---- mixed K|V tile: cols 0..127 = K ([m][136]), 128..191 = V (tr) ----
#pragma unroll
    for (int ni = 0; ni < 3; ++ni) {
      int n = wn * 48 + ni * 16 + col;
      int ng = n0 + n;
      if (ng < 2048) {
        float bvv = bk[ng & 1023];
#pragma unroll
        for (int mi = 0; mi < 8; ++mi) {
          int mrow = wm * 128 + mi * 16 + quad * 4;
#pragma unroll
          for (int r = 0; r < 4; ++r)
            lds[(mrow + r) * 136 + n] = __float2bfloat16(acc[mi][ni][r] + bvv);
        }
      } else {
        int vn = n - 128;
        float bvv = bv[ng & 1023];
#pragma unroll
        for (int mi = 0; mi < 8; ++mi) {
          int m = wm * 128 + mi * 16 + quad * 4;
          union { unsigned u[2]; unsigned long long ull; } pkd;
          pkd.u[0] = pk2(acc[mi][ni][0] + bvv, acc[mi][ni][1] + bvv);
          pkd.u[1] = pk2(acc[mi][ni][2] + bvv, acc[mi][ni][3] + bvv);
          *(unsigned long long*)(lds + 34816 + vn * 264 + m) = pkd.ull;
        }
      }
    }
    barrier_raw();
#pragma unroll
    for (int p = 0; p < 8; ++p) {       // K-part: 256 rows x 16 segs
      int u = p * 512 + t;
      int row = u >> 4, cl = (u & 15) * 8;
      int within = (n0 + cl) & 1023;
      int h = within >> 6, d = within & 63;
      *(bfrag*)(K_ + ((long)((b << 4) + h) * 2048 + sbase + row) * 64 + d) =
          *(const bfrag*)(lds + row * 136 + cl);
    }
#pragma unroll
    for (int p = 0; p < 4; ++p) {       // V-part: 64 rows x 32 segs
      int u = p * 512 + t;
      int vn = u >> 5, seg = (u & 31) * 8;
      int within = (n0 + 128 + vn) & 1023;
      int h = within >> 6, d = within & 63;
      *(bfrag*)(Vt + ((long)((b << 4) + h) * 64 + d) * 2048 + sbase + seg) =
          *(const bfrag*)(lds + 34816 + vn * 264 + seg);
    }
  } else {
    // ---- pure V tile: transposed [n][264] stage, packed b64 writes ----
#pragma unroll
    for (int ni = 0; ni < 3; ++ni) {
      int n = wn * 48 + ni * 16 + col;
      int ng = n0 + n;
      float bvv = bv[ng & 1023];
#pragma unroll
      for (int mi = 0; mi < 8; ++mi) {
        int m = wm * 128 + mi * 16 + quad * 4;
        union { unsigned u[2]; unsigned long long ull; } pkd;
        pkd.u[0] = pk2(acc[mi][ni][0] + bvv, acc[mi][ni][1] + bvv);
        pkd.u[1] = pk2(acc[mi][ni][2] + bvv, acc[mi][ni][3] + bvv);
        *(unsigned long long*)(lds + n * 264 + m) = pkd.ull;
      }
    }
    barrier_raw();
#pragma unroll
    for (int p = 0; p < 12; ++p) {      // 192 rows x 32 segs
      int u = p * 512 + t;
      int rn = u >> 5, seg = (u & 31) * 8;
      int within = (n0 + rn) & 1023;
      int h = within >> 6, d = within & 63;
      *(bfrag*)(Vt + ((long)((b << 4) + h) * 64 + d) * 2048 + sbase + seg) =
          *(const bfrag*)(lds + rn * 264 + seg);
    }
  }
}

// ---------------- out-projection: 128x64, BK=64, gload_lds dbuf -----------
// 2-phase template; LDS tile [rows][64], swizzle slot s^(r&7).
__global__ __launch_bounds__(256) void gemm_out(const bf16* __restrict__ O,
                                                const bf16* __restrict__ Bt,
                                                float* __restrict__ Cf) {
  const int K = 1024;
  __shared__ bf16 As[2][128 * 64];
  __shared__ bf16 Bs[2][64 * 64];
  int id = blockIdx.x;
  int xcd = id & 7, sw = id >> 3;
  int m0 = ((xcd << 2) | (sw & 3)) * 128;
  int n0 = (sw >> 2) * 64;
  int t = threadIdx.x;
  int wave = t >> 6, lane = t & 63, quad = lane >> 4, col = lane & 15;
  int wr = (wave >> 1) * 64, wc = (wave & 1) * 32;
  f32x4 acc[2][4] = {};

  int schunk = 8 * ((t & 7) ^ ((t >> 3) & 7));
  int ob = m0 >> 11;
  const bf16* AsrcB = O + (long)ob * 2097152 + (long)((m0 & 2047) + (t >> 3)) * 64 + schunk;
  const bf16* BsrcB = Bt + (long)(n0 + (t >> 3)) * K + schunk;
  int wv = wave * 512;
  int xoff0 = (quad * 8) ^ ((col & 7) << 3);

#define OUT_STAGE(bi, k0n)                                                 \
  {                                                                        \
    long ko = ((long)((k0n) >> 6)) * 131072;                               \
    _Pragma("unroll") for (int i = 0; i < 4; ++i)                          \
      gload16(AsrcB + ko + (long)(32 * i) * 64, &As[bi][i * 2048 + wv]);   \
    _Pragma("unroll") for (int i = 0; i < 2; ++i)                          \
      gload16(BsrcB + (k0n) + (long)(32 * i) * K, &Bs[bi][i * 2048 + wv]); \
  }

  OUT_STAGE(0, 0);
  __syncthreads();
  for (int k0 = 0; k0 < K; k0 += 64) {
    int cur = (k0 >> 6) & 1;
    if (k0 + 64 < K) OUT_STAGE(cur ^ 1, k0 + 64);
#pragma unroll
    for (int kc = 0; kc < 2; ++kc) {
      int xk = xoff0 ^ (kc * 32);
      bfrag ra[4], rb[2];
#pragma unroll
      for (int i = 0; i < 4; ++i)
        ra[i] = *(const bfrag*)(&As[cur][(wr + 16 * i + col) * 64 + xk]);
#pragma unroll
      for (int c = 0; c < 2; ++c)
        rb[c] = *(const bfrag*)(&Bs[cur][(wc + 16 * c + col) * 64 + xk]);
#pragma unroll
      for (int c = 0; c < 2; ++c)
#pragma unroll
        for (int i = 0; i < 4; ++i) acc[c][i] = MFMA16(ra[i], rb[c], acc[c][i]);
    }
    __syncthreads();
  }
#undef OUT_STAGE

#pragma unroll
  for (int c = 0; c < 2; ++c) {
    int n = n0 + wc + 16 * c + col;
#pragma unroll
    for (int i = 0; i < 4; ++i)
#pragma unroll
      for (int r = 0; r < 4; ++r) {
        int m = m0 + wr + 16 * i + quad * 4 + r;
        Cf[(long)m * 1024 + n] = acc[c][i][r];
      }
  }
}

// ---------------- flash attention: S^T dataflow, 2-barrier pipeline -------
// (R17-proven version.)
__global__ __launch_bounds__(256) void attn_kernel(const bf16* __restrict__ Q,
                                                   const bf16* __restrict__ K_,
                                                   const bf16* __restrict__ Vt,
                                                   bf16* __restrict__ O) {
  int id = blockIdx.x;             // 1024 blocks
  int xcd = id & 7, jj = id >> 3;
  int qt = 31 - (jj >> 2);         // LPT
  int bh = ((jj & 3) << 3) | xcd;  // 4 bh per XCD

  __shared__ bf16 Ks[128][72];     // [j][d]; f32 Osc[64][68] overlay in epilogue
  __shared__ bf16 Vs[64][136];     // [d][j]; Lsc + Of overlay in epilogue

  int t = threadIdx.x, wave = t >> 6, lane = t & 63;
  int qh = wave >> 1, jh = wave & 1, hi = lane >> 5, l5 = lane & 31;

  int krow = t >> 3, kg = (t & 7) * 8;
  int vrow = t >> 4, vg = (t & 15) * 8;
  const bf16* KuBase = K_ + (long)bh * 2048 * 64;
  const bf16* VuBase = Vt + (long)bh * 64 * 2048;
  int kL = krow * 64 + kg;         // lane-const
  int vL = vrow * 2048 + vg;       // lane-const

  int q0 = qt * 64;
  int nj = (qt >> 1) + 1;
  int qi = q0 + 32 * qh + l5;      // this lane's global q index

  bfrag qa[4];
  const bf16* qp = Q + ((long)bh * 2048 + q0 + 32 * qh + l5) * 64 + hi * 8;
#pragma unroll
  for (int kd = 0; kd < 4; ++kd) qa[kd] = *(const bfrag*)(qp + kd * 16);

  f32x16 o0, o1;                   // O^T partials: rows d / d+32, col q
  float lsum = 0.f;                // per-lane: sum over this wave's j-half
#pragma unroll
  for (int r = 0; r < 16; ++r) { o0[r] = 0.f; o1[r] = 0.f; }

  // prefetch j-tile 0 (both K and V)
  bfrag kreg[4], vreg[4];
#pragma unroll
  for (int i = 0; i < 4; ++i) {
    kreg[i] = *(const bfrag*)(KuBase + kL + i * 2048);
    vreg[i] = *(const bfrag*)(VuBase + vL + i * 32768);
  }

  for (int jt = 0; jt < nj; ++jt) {
    int j0 = jt * 128;
    __syncthreads();               // prev iter's Ks/Vs reads complete
#pragma unroll
    for (int i = 0; i < 4; ++i) {
      *(bfrag*)(&Ks[krow + 32 * i][kg]) = kreg[i];
      *(bfrag*)(&Vs[vrow + 16 * i][vg]) = vreg[i];
    }
    int jn = (jt + 1 < nj) ? j0 + 128 : j0;       // uniform
    const bf16* kp = KuBase + (long)jn * 64;      // uniform base
    const bf16* vp = VuBase + jn;                 // uniform base
#pragma unroll
    for (int i = 0; i < 4; ++i) {
      kreg[i] = *(const bfrag*)(kp + kL + i * 2048);
      vreg[i] = *(const bfrag*)(vp + vL + i * 32768);
    }
    __syncthreads();               // Ks/Vs ready for all waves

    bool lastT = (jt == nj - 1);
    // even qt: last tile's jh==1 half (j in [q0+64,q0+128)) is fully masked.
    if (lastT && jh == 1 && ((qt & 1) == 0)) continue;

    // S^T: per wave 64j (own half) x 32q. A = K rows, B = Q rows.
    f32x16 s0, s1;
#pragma unroll
    for (int r = 0; r < 16; ++r) { s0[r] = 0.f; s1[r] = 0.f; }
    __builtin_amdgcn_s_setprio(1);
#pragma unroll
    for (int kd = 0; kd < 4; ++kd) {
      bfrag ka0 = *(const bfrag*)(&Ks[jh * 64 + l5][kd * 16 + hi * 8]);
      bfrag ka1 = *(const bfrag*)(&Ks[jh * 64 + 32 + l5][kd * 16 + hi * 8]);
      s0 = MFMA32(ka0, qa[kd], s0);
      s1 = MFMA32(ka1, qa[kd], s1);
    }
    __builtin_amdgcn_s_setprio(0);

    // softmax in-register; pack P^T bf16 groups (g[jb][0..3] = r0-3,4-7,8-11,12-15)
    unsigned g[2][4][2];
#pragma unroll
    for (int jb = 0; jb < 2; ++jb) {
      float pv[16];
      float ls = 0.f;
#pragma unroll
      for (int r = 0; r < 16; ++r) {
        int jl = (r & 3) + 8 * (r >> 2) + 4 * hi;        // j within 32-block
        int j = j0 + jh * 64 + jb * 32 + jl;
        float sv = jb ? s1[r] : s0[r];
        float p = __builtin_amdgcn_exp2f(sv);
        if (lastT) p = (j <= qi) ? p : 0.f;
        ls += p;
        pv[r] = p;
      }
      lsum += ls;
#pragma unroll
      for (int gg = 0; gg < 4; ++gg) {
        g[jb][gg][0] = pk2(pv[4 * gg], pv[4 * gg + 1]);
        g[jb][gg][1] = pk2(pv[4 * gg + 2], pv[4 * gg + 3]);
      }
    }

    // PV: O^T += V^T * P^T over own j-half
    __builtin_amdgcn_s_setprio(1);
#pragma unroll
    for (int jb = 0; jb < 2; ++jb) {
#pragma unroll
      for (int c = 0; c < 2; ++c) {
        unsigned a0 = g[jb][2 * c][0], a1 = g[jb][2 * c][1];
        unsigned b0 = g[jb][2 * c + 1][0], b1 = g[jb][2 * c + 1][1];
        asm("v_permlane32_swap_b32 %0, %1" : "+v"(a0), "+v"(b0));
        asm("v_permlane32_swap_b32 %0, %1" : "+v"(a1), "+v"(b1));
        union { unsigned u[4]; bfrag f; } pf;
        pf.u[0] = a0;
        pf.u[1] = a1;
        pf.u[2] = b0;
        pf.u[3] = b1;
        int kk = jh * 64 + jb * 32 + c * 16 + hi * 8;
        bfrag av0 = *(const bfrag*)(&Vs[l5][kk]);
        bfrag av1 = *(const bfrag*)(&Vs[32 + l5][kk]);
        o0 = MFMA32(av0, pf.f, o0);
        o1 = MFMA32(av1, pf.f, o1);
      }
    }
    __builtin_amdgcn_s_setprio(0);
  }

  // combine hi-halves of lsum (same q, different j-sets)
  lsum += __shfl_xor(lsum, 32, 64);

  __syncthreads();   // all Ks/Vs reads done; overlay scratch
  float* Osc = (float*)&Ks[0][0];                    // [64 q][68 d]
  float* Lsc = (float*)&Vs[0][0];                    // [64 q]
  bf16* Of = (bf16*)((char*)&Vs[0][0] + 512);        // [64 q][72 d]
  int q = 32 * qh + l5;
  if (jh == 1) {
#pragma unroll
    for (int r = 0; r < 16; ++r) {
      int d = (r & 3) + 8 * (r >> 2) + 4 * hi;
      Osc[q * 68 + d] = o0[r];
      Osc[q * 68 + 32 + d] = o1[r];
    }
    if (hi == 0) Lsc[q] = lsum;
  }
  __syncthreads();
  if (jh == 0) {
    float inv = 1.f / (lsum + Lsc[q]);
#pragma unroll
    for (int r = 0; r < 16; ++r) {
      int d = (r & 3) + 8 * (r >> 2) + 4 * hi;
      Of[q * 72 + d] = __float2bfloat16((o0[r] + Osc[q * 68 + d]) * inv);
      Of[q * 72 + 32 + d] = __float2bfloat16((o1[r] + Osc[q * 68 + 32 + d]) * inv);
    }
  }
  __syncthreads();
  int row = t >> 2, off = (t & 3) * 16;
  bf16* po = O + ((long)bh * 2048 + q0 + row) * 64 + off;
  *(bfrag*)(po) = *(const bfrag*)(&Of[row * 72 + off]);
  *(bfrag*)(po + 8) = *(const bfrag*)(&Of[row * 72 + off + 8]);
}

extern "C" void kernel_launch(void* const* d_in, const int* in_sizes, int n_in,
                              void* d_out, int out_size, void* d_ws, size_t ws_size,
                              hipStream_t stream) {
  const float* x  = (const float*)d_in[0];
  const float* Wq = (const float*)d_in[1];
  const float* bq = (const float*)d_in[2];
  const float* Wk = (const float*)d_in[3];
  const float* bk = (const float*)d_in[4];
  const float* Wv = (const float*)d_in[5];
  const float* bv = (const float*)d_in[6];
  const float* Wo = (const float*)d_in[7];
  float* out = (float*)d_out;

  bf16* ws = (bf16*)d_ws;
  const long MB1 = 1 << 20;
  bf16* WqkvT = ws + 0 * MB1;    // [3072][1024]
  bf16* WoT   = ws + 3 * MB1;
  bf16* Q     = ws + 4 * MB1;    // [b][h][s][d]
  bf16* K_    = ws + 8 * MB1;    // [b][h][s][d]
  bf16* Vt    = ws + 12 * MB1;   // [b][h][d][s]
  bf16* O     = ws + 16 * MB1;   // [b][h][s][d]
  bf16* xb    = ws + 20 * MB1;

  prep_all<<<3072, 256, 0, stream>>>(x, Wq, Wk, Wv, Wo, xb, WqkvT, WoT);
  gemm_qkv128<<<256, 512, 114688, stream>>>(xb, WqkvT, bq, bk, bv, Q, K_, Vt);
  attn_kernel<<<1024, 256, 0, stream>>>(Q, K_, Vt, O);
  gemm_out<<<512, 256, 0, stream>>>(O, WoT, out);
}